// Round 7
// baseline (4043.406 us; speedup 1.0000x reference)
//
#include <hip/hip_runtime.h>
#include <stdint.h>

// ---------------- problem constants ----------------
#define Bb    4
#define Tt    4096
#define DM    512
#define DIN_  1024
#define BT_   16384        // Bb*Tt
#define NW    31           // entropy windows: (4096-256)/128+1
#define DSTATE_ 16
#define NWIN  124          // Bb*NW

typedef float f32x4 __attribute__((ext_vector_type(4)));
typedef short s16x8 __attribute__((ext_vector_type(8)));

static __device__ __forceinline__ float bf2f(unsigned short h){
  union { unsigned int u; float f; } v; v.u = ((unsigned int)h)<<16; return v.f;
}
static __device__ __forceinline__ unsigned short f2bf(float f){
  union { float f; unsigned int u; } v; v.f = f;
  unsigned int u = v.u + 0x7fffu + ((v.u>>16)&1u);   // RTNE
  return (unsigned short)(u>>16);
}
static __device__ __forceinline__ float gelu_f(float x){
  return 0.5f*x*(1.0f+erff(x*0.7071067811865476f));
}

__global__ void diag_k(float* out, float v){ out[0] = v; }

// ---------------- LayerNorm: 64-token tiles -> xnT (f32 T) + xnTH (bf16 T) + xnH (bf16 row) ----------------
__global__ __launch_bounds__(256)
void ln_kernel(const float* __restrict__ x, const float* __restrict__ g,
               const float* __restrict__ be, float* __restrict__ xnT,
               unsigned short* __restrict__ xnTH, unsigned short* __restrict__ xnH)
{
  __shared__ float mrs[64][2];
  __shared__ __align__(16) float tile[64][33];
  int tid = threadIdx.x, lane = tid&63, wv = tid>>6;
  int r0 = blockIdx.x*64;
  for (int j=0;j<16;j++){
    int r = r0 + wv*16 + j;
    const float4* px = (const float4*)(x + (size_t)r*DM);
    float4 a = px[lane*2], b4 = px[lane*2+1];
    float s1 = a.x+a.y+a.z+a.w + b4.x+b4.y+b4.z+b4.w;
    float s2 = a.x*a.x+a.y*a.y+a.z*a.z+a.w*a.w + b4.x*b4.x+b4.y*b4.y+b4.z*b4.z+b4.w*b4.w;
    #pragma unroll
    for (int o=32;o>=1;o>>=1){ s1 += __shfl_xor(s1,o); s2 += __shfl_xor(s2,o); }
    if (lane==0){
      float m = s1*(1.f/DM);
      float var = s2*(1.f/DM) - m*m;
      mrs[wv*16+j][0] = m;
      mrs[wv*16+j][1] = rsqrtf(var + 1e-5f);
    }
  }
  __syncthreads();
  for (int d0=0; d0<DM; d0+=32){
    #pragma unroll
    for (int q=0;q<8;q++){
      int tk = q*8 + (tid>>5);
      int dj = tid & 31;
      int r = r0+tk, d = d0+dj;
      float v = x[(size_t)r*DM + d];
      float nv = (v - mrs[tk][0])*mrs[tk][1]*g[d] + be[d];
      tile[tk][dj] = nv;
      xnH[(size_t)r*DM + d] = f2bf(nv);
    }
    __syncthreads();
    #pragma unroll
    for (int q=0;q<8;q++){
      int dj = q*4 + (tid>>6);
      int tk = tid & 63;
      float v = tile[tk][dj];
      xnT [(size_t)(d0+dj)*BT_ + r0 + tk] = v;
      xnTH[(size_t)(d0+dj)*BT_ + r0 + tk] = f2bf(v);
    }
    __syncthreads();
  }
}

// ---------------- weight transpose + f32->bf16: (E,K,N) -> (E,Npad,K) ----------------
__global__ __launch_bounds__(256)
void transpose_cvt(const float* __restrict__ src, unsigned short* __restrict__ dst,
                   int K, int N, int Npad)
{
  __shared__ float tile[32][33];
  int e = blockIdx.z;
  int n0 = blockIdx.x<<5, k0 = blockIdx.y<<5;
  int tx = threadIdx.x & 31, ty = threadIdx.x >> 5;
  #pragma unroll
  for (int i=0;i<4;i++){
    int k = k0 + ty + i*8, n = n0 + tx;
    float v = (n < N) ? src[((size_t)e*K + k)*N + n] : 0.f;
    tile[ty+i*8][tx] = v;
  }
  __syncthreads();
  #pragma unroll
  for (int i=0;i<4;i++){
    int n = n0 + ty + i*8, k = k0 + tx;
    if (n < Npad) dst[((size_t)e*Npad + n)*K + k] = f2bf(tile[tx][ty+i*8]);
  }
}

// ---------------- DFT weight matrix: 256 rows (n<128: cos bin n+1; n>=128: sin bin n-127), 256 k ----------------
__global__ void dft_init(unsigned short* __restrict__ w)
{
  int n = blockIdx.x, k = threadIdx.x;
  int bin = (n < 128) ? n+1 : n-127;
  int idx = (bin*k) & 255;                    // exact integer angle reduction
  float ang = 6.283185307179586f * (float)idx / 256.f;
  float sv, cv; sincosf(ang, &sv, &cv);
  w[n*256 + k] = f2bf((n < 128) ? cv : sv);
}

// ---------------- DFT GEMM: per (window, d-block) 128x128x256 bf16 MFMA ----------------
__global__ __launch_bounds__(256,2)
void dft_gemm(const unsigned short* __restrict__ xnTH, const unsigned short* __restrict__ dftW,
              float* __restrict__ dftO)
{
  __shared__ unsigned short As[128*72];
  __shared__ unsigned short Bs[128*72];
  int tid = threadIdx.x, lane = tid&63, wv = tid>>6;
  int wm = wv>>1, wn = wv&1;
  int win = blockIdx.y >> 2, dblk = blockIdx.y & 3;
  int woff = (win/NW)*Tt + (win%NW)*128;
  int mb = dblk*128;
  int nb = blockIdx.x*128;
  int g4 = (lane>>4)<<2;
  int r16 = lane & 15;
  f32x4 acc[4][4];
  #pragma unroll
  for (int i=0;i<4;i++)
    #pragma unroll
    for (int j=0;j<4;j++) acc[i][j] = (f32x4){0.f,0.f,0.f,0.f};

  for (int k0=0; k0<256; k0+=64) {
    #pragma unroll
    for (int i=0;i<4;i++){
      int c  = tid + (i<<8);
      int r  = c>>3, ko = (c&7)<<3;
      uint4 va = *(const uint4*)(xnTH + (size_t)(mb+r)*BT_ + woff + k0+ko);
      uint4 vb = *(const uint4*)(dftW + (size_t)(nb+r)*256 + k0+ko);
      *(uint4*)&As[r*72+ko] = va;
      *(uint4*)&Bs[r*72+ko] = vb;
    }
    __syncthreads();
    #pragma unroll
    for (int ks=0; ks<2; ks++){
      int kb = ks<<5;
      s16x8 fa[4], fb[4];
      #pragma unroll
      for (int mi=0;mi<4;mi++){
        const unsigned short* p = &As[(wm*64+mi*16+r16)*72 + kb + g4];
        union { uint64_t q[2]; s16x8 v; } u;
        u.q[0] = *(const uint64_t*)p;
        u.q[1] = *(const uint64_t*)(p+16);
        fa[mi] = u.v;
      }
      #pragma unroll
      for (int ni=0;ni<4;ni++){
        const unsigned short* p = &Bs[(wn*64+ni*16+r16)*72 + kb + g4];
        union { uint64_t q[2]; s16x8 v; } u;
        u.q[0] = *(const uint64_t*)p;
        u.q[1] = *(const uint64_t*)(p+16);
        fb[ni] = u.v;
      }
      #pragma unroll
      for (int mi=0;mi<4;mi++)
        #pragma unroll
        for (int ni=0;ni<4;ni++)
          acc[mi][ni] = __builtin_amdgcn_mfma_f32_16x16x32_bf16(fa[mi], fb[ni], acc[mi][ni], 0,0,0);
    }
    __syncthreads();
  }
  #pragma unroll
  for (int mi=0;mi<4;mi++){
    #pragma unroll
    for (int ni=0;ni<4;ni++){
      #pragma unroll
      for (int rr=0;rr<4;rr++){
        int row = win*512 + mb + wm*64 + mi*16 + g4 + rr;
        int col = nb + wn*64 + ni*16 + r16;
        dftO[(size_t)row*256 + col] = acc[mi][ni][rr];
      }
    }
  }
}

// ---------------- entropy reduce: one wave per (window,d) row ----------------
__global__ __launch_bounds__(256)
void ent_reduce(const float* __restrict__ dftO, const unsigned short* __restrict__ xnTH,
                float* __restrict__ ent_partial)
{
  int tid = threadIdx.x, lane = tid&63, wv = tid>>6;
  int row = blockIdx.x*4 + wv;            // 0..63487
  int win = row >> 9, d = row & 511;
  int b = win / NW, w = win - b*NW;
  size_t sb = (size_t)d*BT_ + (size_t)b*Tt + (size_t)w*128;
  union { uint64_t q; unsigned short s[4]; } u;
  u.q = *(const uint64_t*)(xnTH + sb + lane*4);
  float lsum = bf2f(u.s[0])+bf2f(u.s[1])+bf2f(u.s[2])+bf2f(u.s[3]);
  #pragma unroll
  for (int o=32;o>=1;o>>=1) lsum += __shfl_xor(lsum,o);
  const float* r = dftO + (size_t)row*256;
  float c1 = r[lane], c2 = r[64+lane], s1 = r[128+lane], s2 = r[192+lane];
  float m1 = sqrtf(c1*c1+s1*s1) + 1e-10f;
  float m2 = sqrtf(c2*c2+s2*s2) + 1e-10f;
  float m0 = fabsf(lsum) + 1e-10f;
  float ps = m1 + m2 + ((lane==0)? m0 : 0.f);
  #pragma unroll
  for (int o=32;o>=1;o>>=1) ps += __shfl_xor(ps,o);
  float inv = 1.f/ps;
  float p1 = m1*inv, p2 = m2*inv;
  float es = -p1*logf(p1+1e-10f) - p2*logf(p2+1e-10f);
  if (lane==0){ float p0 = m0*inv; es -= p0*logf(p0+1e-10f); }
  #pragma unroll
  for (int o=32;o>=1;o>>=1) es += __shfl_xor(es,o);
  if (lane==0) atomicAdd(&ent_partial[b*NW+w], es*(1.f/4.859812404361672f)); // /ln(129)
}

// ---------------- gating: 64-token tiles, coalesced xnT reads ----------------
__global__ __launch_bounds__(256)
void gating_kernel(const float* __restrict__ xnT, const float* __restrict__ gw,
                   const float* __restrict__ entw, const float* __restrict__ entb,
                   const float* __restrict__ temp, const float* __restrict__ ent_partial,
                   float* __restrict__ wfull, float* __restrict__ g_tpe, float* __restrict__ g_avg)
{
  __shared__ __align__(16) float accs[4][64][8];
  __shared__ float l_tpe[8], l_avg[8];
  int tid = threadIdx.x, lane = tid&63, wv = tid>>6;
  int r0 = blockIdx.x*64;
  if (tid < 8){ l_tpe[tid]=0.f; l_avg[tid]=0.f; }
  float acc[8];
  #pragma unroll
  for (int e=0;e<8;e++) acc[e]=0.f;
  for (int i=0;i<128;i++){
    int dd = wv*128 + i;
    float xv = xnT[(size_t)dd*BT_ + r0 + lane];
    const float4* g4p = (const float4*)(gw + (size_t)dd*8);
    float4 w0 = g4p[0], w1 = g4p[1];
    acc[0]+=xv*w0.x; acc[1]+=xv*w0.y; acc[2]+=xv*w0.z; acc[3]+=xv*w0.w;
    acc[4]+=xv*w1.x; acc[5]+=xv*w1.y; acc[6]+=xv*w1.z; acc[7]+=xv*w1.w;
  }
  #pragma unroll
  for (int e=0;e<8;e++) accs[wv][lane][e] = acc[e];
  __syncthreads();
  if (wv==0){
    int r = r0 + lane;
    int b = r0 >> 12;
    float ep = 0.f;
    for (int i=0;i<NW;i++) ep += ent_partial[b*NW+i];
    float ent = ep * (1.f/(NW*512.f));
    float lg[8];
    #pragma unroll
    for (int e=0;e<8;e++)
      lg[e] = accs[0][lane][e]+accs[1][lane][e]+accs[2][lane][e]+accs[3][lane][e];
    float invT = 1.f/(fabsf(temp[0])+1e-6f);
    #pragma unroll
    for (int e=0;e<8;e++) lg[e] = (lg[e] + ent*entw[e] + entb[e]) * invT;
    int i0=0; float v0=lg[0];
    #pragma unroll
    for (int e=1;e<8;e++) if (lg[e] > v0){ v0=lg[e]; i0=e; }
    int i1=-1; float v1=-1e30f;
    #pragma unroll
    for (int e=0;e<8;e++) if (e!=i0 && lg[e] > v1){ v1=lg[e]; i1=e; }
    float e1 = expf(v1-v0);
    float rw0 = 1.f/(1.f+e1), rw1 = e1/(1.f+e1);
    float pr[8], se=0.f;
    #pragma unroll
    for (int e=0;e<8;e++){ pr[e]=expf(lg[e]-v0); se+=pr[e]; }
    float ise = 1.f/se;
    #pragma unroll
    for (int e=0;e<8;e++) wfull[(size_t)r*8+e] = (e==i0)?rw0 : ((e==i1)?rw1 : 0.f);
    atomicAdd(&l_tpe[i0],1.f); atomicAdd(&l_tpe[i1],1.f);
    #pragma unroll
    for (int e=0;e<8;e++) atomicAdd(&l_avg[e], pr[e]*ise);
  }
  __syncthreads();
  if (tid < 8){ atomicAdd(&g_tpe[tid], l_tpe[tid]); atomicAdd(&g_avg[tid], l_avg[tid]); }
}

__global__ void aux_kernel(const float* __restrict__ g_tpe, const float* __restrict__ g_avg,
                           float* __restrict__ out)
{
  float a=0.f;
  #pragma unroll
  for (int e=0;e<8;e++) a += (g_tpe[e]*(1.f/BT_)) * (g_avg[e]*(1.f/BT_));
  out[(size_t)BT_*DM] = 8.f*a;
}

// ---------------- depthwise causal convs (8 channels / thread) ----------------
__global__ __launch_bounds__(256)
void dwconv7_gelu(const unsigned short* __restrict__ H1, const float* __restrict__ k7,
                  const float* __restrict__ kb, unsigned short* __restrict__ H2)
{
  size_t gid = (size_t)blockIdx.x*256 + threadIdx.x;
  int dg = (int)(gid & 127);
  size_t row = gid >> 7;
  int t = (int)(row & (Tt-1));
  int d0 = dg*8;
  float acc[8];
  #pragma unroll
  for (int i=0;i<8;i++) acc[i] = kb[d0+i];
  #pragma unroll
  for (int j=0;j<7;j++){
    int off = 6-j;
    if (t - off >= 0){
      union { uint4 v; unsigned short s[8]; } u;
      u.v = *(const uint4*)(H1 + (row-(size_t)off)*DIN_ + d0);
      #pragma unroll
      for (int i=0;i<8;i++) acc[i] += bf2f(u.s[i]) * k7[(size_t)(d0+i)*7+j];
    }
  }
  union { uint4 v; unsigned short s[8]; } o;
  #pragma unroll
  for (int i=0;i<8;i++) o.s[i] = f2bf(gelu_f(acc[i]));
  *(uint4*)(H2 + row*DIN_ + d0) = o.v;
}

__global__ __launch_bounds__(256)
void dwconv4_silu(const unsigned short* __restrict__ U, const float* __restrict__ cw,
                  const float* __restrict__ cb, unsigned short* __restrict__ uH)
{
  size_t gid = (size_t)blockIdx.x*256 + threadIdx.x;
  int dg = (int)(gid & 127);
  size_t row = gid >> 7;
  int t = (int)(row & (Tt-1));
  int d0 = dg*8;
  float acc[8];
  #pragma unroll
  for (int i=0;i<8;i++) acc[i] = cb[d0+i];
  #pragma unroll
  for (int j=0;j<4;j++){
    int off = 3-j;
    if (t - off >= 0){
      union { uint4 v; unsigned short s[8]; } u;
      u.v = *(const uint4*)(U + (row-(size_t)off)*DIN_ + d0);
      #pragma unroll
      for (int i=0;i<8;i++) acc[i] += bf2f(u.s[i]) * cw[(size_t)(d0+i)*4+j];
    }
  }
  union { uint4 v; unsigned short s[8]; } o;
  #pragma unroll
  for (int i=0;i<8;i++){ float v = acc[i]; o.s[i] = f2bf(v/(1.f+expf(-v))); }
  *(uint4*)(uH + row*DIN_ + d0) = o.v;
}

// ---------------- chunk-parallel selective scan with fused delta (128-step chunks) ----------------
__global__ __launch_bounds__(256)
void scan_k(const float* __restrict__ dbc, const unsigned short* __restrict__ uH,
            const unsigned short* __restrict__ zH,
            const float* __restrict__ dtw, const float* __restrict__ dtb,
            const float* __restrict__ Alog, const float* __restrict__ Dp,
            unsigned short* __restrict__ yH)
{
  int tid = threadIdx.x;
  int blk = blockIdx.x;
  int dblk = blk & 3, chunk = (blk>>2) & 31, b = blk>>7;
  int d = dblk*256 + tid;
  int t0 = chunk*128, t1 = t0+128;
  int t = (t0 >= 64) ? t0-64 : 0;
  float wk[32];
  #pragma unroll
  for (int k=0;k<32;k++) wk[k] = dtw[(size_t)k*DIN_ + d];
  float dtbv = dtb[d];
  float As[DSTATE_];
  bool fastb = true;
  #pragma unroll
  for (int s=0;s<DSTATE_;s++){
    As[s] = -expf(Alog[(size_t)d*DSTATE_+s]);
    if (fabsf(As[s] + (float)(s+1)) > 1e-3f) fastb=false;
  }
  int fast = __all((int)fastb);
  float Dv = Dp[d];
  float h[DSTATE_];
  #pragma unroll
  for (int s=0;s<DSTATE_;s++) h[s]=0.f;
  for (; t<t1; ++t){
    size_t row = ((size_t)b<<12) + t;
    const float* rowp = dbc + row*128;
    float p0=0.f,p1=0.f,p2=0.f,p3=0.f;
    #pragma unroll
    for (int k=0;k<32;k+=4){
      p0 += rowp[k]*wk[k];   p1 += rowp[k+1]*wk[k+1];
      p2 += rowp[k+2]*wk[k+2]; p3 += rowp[k+3]*wk[k+3];
    }
    float s0 = dtbv + ((p0+p1)+(p2+p3));
    float dl = (s0 > 20.f) ? s0 : log1pf(expf(s0));
    float u  = bf2f(uH[row*DIN_+d]);
    float Bv[DSTATE_], Cv[DSTATE_];
    const float4* pb = (const float4*)(rowp + 32);
    const float4* pc = (const float4*)(rowp + 48);
    #pragma unroll
    for (int q=0;q<4;q++){
      float4 fb_ = pb[q]; Bv[4*q]=fb_.x; Bv[4*q+1]=fb_.y; Bv[4*q+2]=fb_.z; Bv[4*q+3]=fb_.w;
      float4 fc_ = pc[q]; Cv[4*q]=fc_.x; Cv[4*q+1]=fc_.y; Cv[4*q+2]=fc_.z; Cv[4*q+3]=fc_.w;
    }
    float du = dl*u;
    if (fast){
      float e1 = __expf(-dl);
      float pw = e1;
      #pragma unroll
      for (int s=0;s<DSTATE_;s++){ h[s] = pw*h[s] + du*Bv[s]; pw *= e1; }
    } else {
      #pragma unroll
      for (int s=0;s<DSTATE_;s++){ float a = __expf(dl*As[s]); h[s] = a*h[s] + du*Bv[s]; }
    }
    if (t >= t0){
      float y = 0.f;
      #pragma unroll
      for (int s=0;s<DSTATE_;s++) y += h[s]*Cv[s];
      y += u*Dv;
      float z = bf2f(zH[row*DIN_+d]);
      float sil = z/(1.f+expf(-z));
      yH[row*DIN_+d] = f2bf(y*sil);
    }
  }
}

// ---------------- bf16 MFMA GEMM, 128x128 tile, BK=64, reg-staged padded LDS ----------------
enum { E_GELU_BF16=0, E_BF16=1, E_F32=2, E_MOE=3 };

template<int EPI>
__global__ __launch_bounds__(256,2)
void gemm_k(const unsigned short* __restrict__ A, int lda,
            const unsigned short* __restrict__ Bm, int ldb,
            int K,
            const float* __restrict__ bias,
            float* __restrict__ oF, unsigned short* __restrict__ oH, int ldo,
            const float* __restrict__ wfull, int ecol,
            const float* __restrict__ resid,
            unsigned short* __restrict__ oH2)
{
  __shared__ unsigned short As[128*72];
  __shared__ unsigned short Bs[128*72];
  int tid = threadIdx.x, lane = tid&63, wv = tid>>6;
  int wm = wv>>1, wn = wv&1;
  int nwg = gridDim.x*gridDim.y;
  int wg  = blockIdx.y*gridDim.x + blockIdx.x;
  int cpx = nwg >> 3;
  int swz = (wg & 7)*cpx + (wg >> 3);
  int bx = swz % gridDim.x, by = swz / gridDim.x;
  int mb = by*128, nb = bx*128;
  int g4 = (lane>>4)<<2;
  int r16 = lane & 15;
  f32x4 acc[4][4];
  #pragma unroll
  for (int i=0;i<4;i++)
    #pragma unroll
    for (int j=0;j<4;j++) acc[i][j] = (f32x4){0.f,0.f,0.f,0.f};

  for (int k0=0; k0<K; k0+=64) {
    #pragma unroll
    for (int i=0;i<4;i++){
      int c  = tid + (i<<8);
      int r  = c>>3, ko = (c&7)<<3;
      uint4 va = *(const uint4*)(A  + (size_t)(mb+r)*lda + k0+ko);
      uint4 vb = *(const uint4*)(Bm + (size_t)(nb+r)*ldb + k0+ko);
      *(uint4*)&As[r*72+ko] = va;
      *(uint4*)&Bs[r*72+ko] = vb;
    }
    __syncthreads();
    #pragma unroll
    for (int ks=0; ks<2; ks++){
      int kb = ks<<5;
      s16x8 fa[4], fb[4];
      #pragma unroll
      for (int mi=0;mi<4;mi++){
        const unsigned short* p = &As[(wm*64+mi*16+r16)*72 + kb + g4];
        union { uint64_t q[2]; s16x8 v; } u;
        u.q[0] = *(const uint64_t*)p;
        u.q[1] = *(const uint64_t*)(p+16);
        fa[mi] = u.v;
      }
      #pragma unroll
      for (int ni=0;ni<4;ni++){
        const unsigned short* p = &Bs[(wn*64+ni*16+r16)*72 + kb + g4];
        union { uint64_t q[2]; s16x8 v; } u;
        u.q[0] = *(const uint64_t*)p;
        u.q[1] = *(const uint64_t*)(p+16);
        fb[ni] = u.v;
      }
      #pragma unroll
      for (int mi=0;mi<4;mi++)
        #pragma unroll
        for (int ni=0;ni<4;ni++)
          acc[mi][ni] = __builtin_amdgcn_mfma_f32_16x16x32_bf16(fa[mi], fb[ni], acc[mi][ni], 0,0,0);
    }
    __syncthreads();
  }
  #pragma unroll
  for (int mi=0;mi<4;mi++){
    #pragma unroll
    for (int ni=0;ni<4;ni++){
      #pragma unroll
      for (int rr=0;rr<4;rr++){
        int row = mb + wm*64 + mi*16 + g4 + rr;
        int col = nb + wn*64 + ni*16 + r16;
        float v = acc[mi][ni][rr];
        if constexpr (EPI == E_GELU_BF16){
          v += bias[col];
          oH[(size_t)row*ldo + col] = f2bf(gelu_f(v));
        } else if constexpr (EPI == E_BF16){
          if (bias) v += bias[col];
          if (oH2 && col >= 1024) oH2[(size_t)row*1024 + col - 1024] = f2bf(v);
          else                    oH [(size_t)row*ldo  + col] = f2bf(v);
        } else if constexpr (EPI == E_F32){
          oF[(size_t)row*ldo + col] = v;
        } else { // E_MOE
          size_t o = (size_t)row*ldo + col;
          if (bias) v += bias[col];
          float w = wfull[(size_t)row*8 + ecol];
          float base = resid ? resid[o] : oF[o];
          oF[o] = base + w*v;
        }
      }
    }
  }
}

extern "C" void kernel_launch(void* const* d_in, const int* in_sizes, int n_in,
                              void* d_out, int out_size, void* d_ws, size_t ws_size,
                              hipStream_t stream)
{
  (void)in_sizes; (void)n_in; (void)out_size;
  const float* x      = (const float*)d_in[0];
  const float* ln_g   = (const float*)d_in[1];
  const float* ln_b   = (const float*)d_in[2];
  const float* gate_w = (const float*)d_in[3];
  const float* ent_w  = (const float*)d_in[4];
  const float* ent_b  = (const float*)d_in[5];
  const float* temp   = (const float*)d_in[6];
  const float* cin_w  = (const float*)d_in[7];
  const float* cin_b  = (const float*)d_in[8];
  const float* ck     = (const float*)d_in[9];
  const float* ck_b   = (const float*)d_in[10];
  const float* cout_w = (const float*)d_in[11];
  const float* cout_b = (const float*)d_in[12];
  const float* m_in   = (const float*)d_in[13];
  const float* m_cw   = (const float*)d_in[14];
  const float* m_cb   = (const float*)d_in[15];
  const float* m_xp   = (const float*)d_in[16];
  const float* m_dtw  = (const float*)d_in[17];
  const float* m_dtb  = (const float*)d_in[18];
  const float* m_alog = (const float*)d_in[19];
  const float* m_Dd   = (const float*)d_in[20];
  const float* m_op   = (const float*)d_in[21];
  float* out = (float*)d_out;
  char* ws = (char*)d_ws;

  size_t off = 0;
  auto alloc = [&](size_t bytes)->size_t{
    size_t r = off; off += (bytes + 4095) & ~(size_t)4095; return r;
  };
  size_t o_xnH  = alloc((size_t)BT_*DM*2);
  size_t o_wf   = alloc((size_t)BT_*8*4);
  size_t o_st   = alloc(4096);
  size_t o_wCI  = alloc((size_t)4*DIN_*DM*2);
  size_t o_wCO  = alloc((size_t)4*DM*DIN_*2);
  size_t o_wIP  = alloc((size_t)4*2048*DM*2);
  size_t o_wXP  = alloc((size_t)4*128*DIN_*2);
  size_t o_wOP  = alloc((size_t)4*DM*DIN_*2);
  size_t o_A0   = alloc((size_t)BT_*DIN_*2);   // u_raw / conv H1 / y   | dftO (with A1)
  size_t o_A1   = alloc((size_t)BT_*DIN_*2);   // z                     | dftO tail
  size_t o_A3   = alloc((size_t)BT_*DIN_*2);   // u' / conv H2          | xnTH (bf16 T)
  size_t o_A4   = alloc((size_t)BT_*128*4);    // dbc f32               | dftW
  size_t o_xnT  = alloc((size_t)BT_*DM*4);     // f32 xn transposed (DM, BT)
  size_t need = off;

  if (ws_size < need){
    diag_k<<<1,1,0,stream>>>(out, (float)(ws_size >> 20));
    return;
  }

  unsigned short* xnH  = (unsigned short*)(ws + o_xnH);
  float*          xnT  = (float*)(ws + o_xnT);
  float*          wfull= (float*)(ws + o_wf);
  float*          entP = (float*)(ws + o_st);
  float*          gtpe = (float*)(ws + o_st + 512);
  float*          gavg = (float*)(ws + o_st + 544);
  unsigned short* wtCI = (unsigned short*)(ws + o_wCI);
  unsigned short* wtCO = (unsigned short*)(ws + o_wCO);
  unsigned short* wtIP = (unsigned short*)(ws + o_wIP);
  unsigned short* wtXP = (unsigned short*)(ws + o_wXP);
  unsigned short* wtOP = (unsigned short*)(ws + o_wOP);
  unsigned short* a0H  = (unsigned short*)(ws + o_A0);
  unsigned short* a1H  = (unsigned short*)(ws + o_A1);
  unsigned short* a3H  = (unsigned short*)(ws + o_A3);
  float*          a4F  = (float*)(ws + o_A4);
  // entropy-phase aliases (used only before experts run)
  float*          dftO = (float*)(ws + o_A0);            // 63488*256*4 = 65 MB < A0+A1
  unsigned short* xnTH = (unsigned short*)(ws + o_A3);   // 16.8 MB < 33.5 MB
  unsigned short* dftW = (unsigned short*)(ws + o_A4);   // 128 KB

  hipMemsetAsync(ws + o_st, 0, 4096, stream);

  transpose_cvt<<<dim3(32,16,4),256,0,stream>>>(cin_w,  wtCI, 512, 1024, 1024);
  transpose_cvt<<<dim3(16,32,4),256,0,stream>>>(cout_w, wtCO, 1024, 512, 512);
  transpose_cvt<<<dim3(64,16,4),256,0,stream>>>(m_in,   wtIP, 512, 2048, 2048);
  transpose_cvt<<<dim3( 4,32,4),256,0,stream>>>(m_xp,   wtXP, 1024, 64, 128);
  transpose_cvt<<<dim3(16,32,4),256,0,stream>>>(m_op,   wtOP, 1024, 512, 512);
  dft_init<<<256,256,0,stream>>>(dftW);

  ln_kernel<<<BT_/64,256,0,stream>>>(x, ln_g, ln_b, xnT, xnTH, xnH);
  dft_gemm<<<dim3(2, NWIN*4),256,0,stream>>>(xnTH, dftW, dftO);
  ent_reduce<<<NWIN*512/4,256,0,stream>>>(dftO, xnTH, entP);
  gating_kernel<<<BT_/64,256,0,stream>>>(xnT, gate_w, ent_w, ent_b, temp, entP, wfull, gtpe, gavg);

  // conv experts (0..3)
  for (int e=0;e<4;e++){
    gemm_k<E_GELU_BF16><<<dim3(8,128),256,0,stream>>>(
        xnH, DM, wtCI + (size_t)e*DIN_*DM, DM, DM,
        cin_b + (size_t)e*DIN_, nullptr, a0H, DIN_, nullptr, 0, nullptr, nullptr);
    dwconv7_gelu<<<BT_*DIN_/8/256,256,0,stream>>>(a0H, ck + (size_t)e*DIN_*7, ck_b + (size_t)e*DIN_, a3H);
    gemm_k<E_MOE><<<dim3(4,128),256,0,stream>>>(
        a3H, DIN_, wtCO + (size_t)e*DM*DIN_, DIN_, DIN_,
        cout_b + (size_t)e*DM, out, nullptr, DM, wfull, e, (e==0)? x : nullptr, nullptr);
  }

  // mamba experts (4..7)
  for (int e=0;e<4;e++){
    gemm_k<E_BF16><<<dim3(16,128),256,0,stream>>>(
        xnH, DM, wtIP + (size_t)e*2048*DM, DM, DM,
        nullptr, nullptr, a0H, DIN_, nullptr, 0, nullptr, a1H);            // u_raw + z split
    dwconv4_silu<<<BT_*DIN_/8/256,256,0,stream>>>(a0H, m_cw + (size_t)e*DIN_*4, m_cb + (size_t)e*DIN_, a3H);
    gemm_k<E_F32><<<dim3(1,128),256,0,stream>>>(
        a3H, DIN_, wtXP + (size_t)e*128*DIN_, DIN_, DIN_,
        nullptr, a4F, nullptr, 128, nullptr, 0, nullptr, nullptr);         // dbc
    scan_k<<<512,256,0,stream>>>(a4F, a3H, a1H,
        m_dtw + (size_t)e*32*DIN_, m_dtb + (size_t)e*DIN_,
        m_alog + (size_t)e*DIN_*DSTATE_, m_Dd + (size_t)e*DIN_, a0H);      // y -> a0H
    gemm_k<E_MOE><<<dim3(4,128),256,0,stream>>>(
        a0H, DIN_, wtOP + (size_t)e*DM*DIN_, DIN_, DIN_,
        nullptr, out, nullptr, DM, wfull, 4+e, nullptr, nullptr);
  }

  aux_kernel<<<1,1,0,stream>>>(gtpe, gavg, out);
}

// Round 8
// 3660.208 us; speedup vs baseline: 1.1047x; 1.1047x over previous
//
#include <hip/hip_runtime.h>
#include <stdint.h>

// ---------------- problem constants ----------------
#define Bb    4
#define Tt    4096
#define DM    512
#define DIN_  1024
#define BT_   16384        // Bb*Tt
#define NW    31           // entropy windows: (4096-256)/128+1
#define DSTATE_ 16
#define NWIN  124          // Bb*NW

typedef float f32x4 __attribute__((ext_vector_type(4)));
typedef short s16x8 __attribute__((ext_vector_type(8)));

static __device__ __forceinline__ float bf2f(unsigned short h){
  union { unsigned int u; float f; } v; v.u = ((unsigned int)h)<<16; return v.f;
}
static __device__ __forceinline__ unsigned short f2bf(float f){
  union { float f; unsigned int u; } v; v.f = f;
  unsigned int u = v.u + 0x7fffu + ((v.u>>16)&1u);   // RTNE
  return (unsigned short)(u>>16);
}
static __device__ __forceinline__ float gelu_f(float x){
  return 0.5f*x*(1.0f+erff(x*0.7071067811865476f));
}

__global__ void diag_k(float* out, float v){ out[0] = v; }

// ---------------- LayerNorm: 64-token tiles -> xnT (f32 T) + xnTH (bf16 T) + xnH (bf16 row) ----------------
__global__ __launch_bounds__(256)
void ln_kernel(const float* __restrict__ x, const float* __restrict__ g,
               const float* __restrict__ be, float* __restrict__ xnT,
               unsigned short* __restrict__ xnTH, unsigned short* __restrict__ xnH)
{
  __shared__ float mrs[64][2];
  __shared__ __align__(16) float tile[64][33];
  int tid = threadIdx.x, lane = tid&63, wv = tid>>6;
  int r0 = blockIdx.x*64;
  for (int j=0;j<16;j++){
    int r = r0 + wv*16 + j;
    const float4* px = (const float4*)(x + (size_t)r*DM);
    float4 a = px[lane*2], b4 = px[lane*2+1];
    float s1 = a.x+a.y+a.z+a.w + b4.x+b4.y+b4.z+b4.w;
    float s2 = a.x*a.x+a.y*a.y+a.z*a.z+a.w*a.w + b4.x*b4.x+b4.y*b4.y+b4.z*b4.z+b4.w*b4.w;
    #pragma unroll
    for (int o=32;o>=1;o>>=1){ s1 += __shfl_xor(s1,o); s2 += __shfl_xor(s2,o); }
    if (lane==0){
      float m = s1*(1.f/DM);
      float var = s2*(1.f/DM) - m*m;
      mrs[wv*16+j][0] = m;
      mrs[wv*16+j][1] = rsqrtf(var + 1e-5f);
    }
  }
  __syncthreads();
  for (int d0=0; d0<DM; d0+=32){
    #pragma unroll
    for (int q=0;q<8;q++){
      int tk = q*8 + (tid>>5);
      int dj = tid & 31;
      int r = r0+tk, d = d0+dj;
      float v = x[(size_t)r*DM + d];
      float nv = (v - mrs[tk][0])*mrs[tk][1]*g[d] + be[d];
      tile[tk][dj] = nv;
      xnH[(size_t)r*DM + d] = f2bf(nv);
    }
    __syncthreads();
    #pragma unroll
    for (int q=0;q<8;q++){
      int dj = q*4 + (tid>>6);
      int tk = tid & 63;
      float v = tile[tk][dj];
      xnT [(size_t)(d0+dj)*BT_ + r0 + tk] = v;
      xnTH[(size_t)(d0+dj)*BT_ + r0 + tk] = f2bf(v);
    }
    __syncthreads();
  }
}

// ---------------- weight transpose + f32->bf16: (E,K,N) -> (E,Npad,K) ----------------
__global__ __launch_bounds__(256)
void transpose_cvt(const float* __restrict__ src, unsigned short* __restrict__ dst,
                   int K, int N, int Npad)
{
  __shared__ float tile[32][33];
  int e = blockIdx.z;
  int n0 = blockIdx.x<<5, k0 = blockIdx.y<<5;
  int tx = threadIdx.x & 31, ty = threadIdx.x >> 5;
  #pragma unroll
  for (int i=0;i<4;i++){
    int k = k0 + ty + i*8, n = n0 + tx;
    float v = (n < N) ? src[((size_t)e*K + k)*N + n] : 0.f;
    tile[ty+i*8][tx] = v;
  }
  __syncthreads();
  #pragma unroll
  for (int i=0;i<4;i++){
    int n = n0 + ty + i*8, k = k0 + tx;
    if (n < Npad) dst[((size_t)e*Npad + n)*K + k] = f2bf(tile[tx][ty+i*8]);
  }
}

// ---------------- DFT weight matrix: 256 rows (n<128: cos bin n+1; n>=128: sin bin n-127), 256 k ----------------
__global__ void dft_init(unsigned short* __restrict__ w)
{
  int n = blockIdx.x, k = threadIdx.x;
  int bin = (n < 128) ? n+1 : n-127;
  int idx = (bin*k) & 255;                    // exact integer angle reduction
  float ang = 6.283185307179586f * (float)idx / 256.f;
  float sv, cv; sincosf(ang, &sv, &cv);
  w[n*256 + k] = f2bf((n < 128) ? cv : sv);
}

// ---------------- DFT GEMM: per (window, d-block) 128x128x256 bf16 MFMA ----------------
__global__ __launch_bounds__(256,2)
void dft_gemm(const unsigned short* __restrict__ xnTH, const unsigned short* __restrict__ dftW,
              float* __restrict__ dftO)
{
  __shared__ unsigned short As[128*72];
  __shared__ unsigned short Bs[128*72];
  int tid = threadIdx.x, lane = tid&63, wv = tid>>6;
  int wm = wv>>1, wn = wv&1;
  int win = blockIdx.y >> 2, dblk = blockIdx.y & 3;
  int woff = (win/NW)*Tt + (win%NW)*128;
  int mb = dblk*128;
  int nb = blockIdx.x*128;
  int g4 = (lane>>4)<<2;
  int r16 = lane & 15;
  f32x4 acc[4][4];
  #pragma unroll
  for (int i=0;i<4;i++)
    #pragma unroll
    for (int j=0;j<4;j++) acc[i][j] = (f32x4){0.f,0.f,0.f,0.f};

  for (int k0=0; k0<256; k0+=64) {
    #pragma unroll
    for (int i=0;i<4;i++){
      int c  = tid + (i<<8);
      int r  = c>>3, ko = (c&7)<<3;
      uint4 va = *(const uint4*)(xnTH + (size_t)(mb+r)*BT_ + woff + k0+ko);
      uint4 vb = *(const uint4*)(dftW + (size_t)(nb+r)*256 + k0+ko);
      *(uint4*)&As[r*72+ko] = va;
      *(uint4*)&Bs[r*72+ko] = vb;
    }
    __syncthreads();
    #pragma unroll
    for (int ks=0; ks<2; ks++){
      int kb = ks<<5;
      s16x8 fa[4], fb[4];
      #pragma unroll
      for (int mi=0;mi<4;mi++){
        const unsigned short* p = &As[(wm*64+mi*16+r16)*72 + kb + g4];
        union { uint64_t q[2]; s16x8 v; } u;
        u.q[0] = *(const uint64_t*)p;
        u.q[1] = *(const uint64_t*)(p+16);
        fa[mi] = u.v;
      }
      #pragma unroll
      for (int ni=0;ni<4;ni++){
        const unsigned short* p = &Bs[(wn*64+ni*16+r16)*72 + kb + g4];
        union { uint64_t q[2]; s16x8 v; } u;
        u.q[0] = *(const uint64_t*)p;
        u.q[1] = *(const uint64_t*)(p+16);
        fb[ni] = u.v;
      }
      #pragma unroll
      for (int mi=0;mi<4;mi++)
        #pragma unroll
        for (int ni=0;ni<4;ni++)
          acc[mi][ni] = __builtin_amdgcn_mfma_f32_16x16x32_bf16(fa[mi], fb[ni], acc[mi][ni], 0,0,0);
    }
    __syncthreads();
  }
  #pragma unroll
  for (int mi=0;mi<4;mi++){
    #pragma unroll
    for (int ni=0;ni<4;ni++){
      #pragma unroll
      for (int rr=0;rr<4;rr++){
        int row = win*512 + mb + wm*64 + mi*16 + g4 + rr;
        int col = nb + wn*64 + ni*16 + r16;
        dftO[(size_t)row*256 + col] = acc[mi][ni][rr];
      }
    }
  }
}

// ---------------- entropy reduce stage 1: one wave per (window,d) row, NO atomics ----------------
__global__ __launch_bounds__(256)
void ent_reduce(const float* __restrict__ dftO, const unsigned short* __restrict__ xnTH,
                float* __restrict__ rowent)
{
  int tid = threadIdx.x, lane = tid&63, wv = tid>>6;
  int row = blockIdx.x*4 + wv;            // 0..63487
  int win = row >> 9, d = row & 511;
  int b = win / NW, w = win - b*NW;
  size_t sb = (size_t)d*BT_ + (size_t)b*Tt + (size_t)w*128;
  union { uint64_t q; unsigned short s[4]; } u;
  u.q = *(const uint64_t*)(xnTH + sb + lane*4);
  float lsum = bf2f(u.s[0])+bf2f(u.s[1])+bf2f(u.s[2])+bf2f(u.s[3]);
  #pragma unroll
  for (int o=32;o>=1;o>>=1) lsum += __shfl_xor(lsum,o);
  const float* r = dftO + (size_t)row*256;
  float c1 = r[lane], c2 = r[64+lane], s1 = r[128+lane], s2 = r[192+lane];
  float m1 = sqrtf(c1*c1+s1*s1) + 1e-10f;
  float m2 = sqrtf(c2*c2+s2*s2) + 1e-10f;
  float m0 = fabsf(lsum) + 1e-10f;
  float ps = m1 + m2 + ((lane==0)? m0 : 0.f);
  #pragma unroll
  for (int o=32;o>=1;o>>=1) ps += __shfl_xor(ps,o);
  float inv = 1.f/ps;
  float p1 = m1*inv, p2 = m2*inv;
  float es = -p1*logf(p1+1e-10f) - p2*logf(p2+1e-10f);
  if (lane==0){ float p0 = m0*inv; es -= p0*logf(p0+1e-10f); }
  #pragma unroll
  for (int o=32;o>=1;o>>=1) es += __shfl_xor(es,o);
  if (lane==0) rowent[row] = es*(1.f/4.859812404361672f);   // /ln(129)
}

// ---------------- entropy reduce stage 2: 124 blocks, sum 512 rows -> entP[win] ----------------
__global__ __launch_bounds__(256)
void ent_stage2(const float* __restrict__ rowent, float* __restrict__ entP)
{
  __shared__ float r4[4];
  int win = blockIdx.x, tid = threadIdx.x, lane = tid&63, wv = tid>>6;
  const float* p = rowent + (size_t)win*512;
  float s = p[tid] + p[tid+256];
  #pragma unroll
  for (int o=32;o>=1;o>>=1) s += __shfl_xor(s,o);
  if (lane==0) r4[wv] = s;
  __syncthreads();
  if (tid==0) entP[win] = r4[0]+r4[1]+r4[2]+r4[3];
}

// ---------------- gating: 64-token tiles, coalesced xnT reads ----------------
__global__ __launch_bounds__(256)
void gating_kernel(const float* __restrict__ xnT, const float* __restrict__ gw,
                   const float* __restrict__ entw, const float* __restrict__ entb,
                   const float* __restrict__ temp, const float* __restrict__ ent_partial,
                   float* __restrict__ wfull, float* __restrict__ g_tpe, float* __restrict__ g_avg)
{
  __shared__ __align__(16) float accs[4][64][8];
  __shared__ float l_tpe[8], l_avg[8];
  int tid = threadIdx.x, lane = tid&63, wv = tid>>6;
  int r0 = blockIdx.x*64;
  if (tid < 8){ l_tpe[tid]=0.f; l_avg[tid]=0.f; }
  float acc[8];
  #pragma unroll
  for (int e=0;e<8;e++) acc[e]=0.f;
  for (int i=0;i<128;i++){
    int dd = wv*128 + i;
    float xv = xnT[(size_t)dd*BT_ + r0 + lane];
    const float4* g4p = (const float4*)(gw + (size_t)dd*8);
    float4 w0 = g4p[0], w1 = g4p[1];
    acc[0]+=xv*w0.x; acc[1]+=xv*w0.y; acc[2]+=xv*w0.z; acc[3]+=xv*w0.w;
    acc[4]+=xv*w1.x; acc[5]+=xv*w1.y; acc[6]+=xv*w1.z; acc[7]+=xv*w1.w;
  }
  #pragma unroll
  for (int e=0;e<8;e++) accs[wv][lane][e] = acc[e];
  __syncthreads();
  if (wv==0){
    int r = r0 + lane;
    int b = r0 >> 12;
    float ep = 0.f;
    for (int i=0;i<NW;i++) ep += ent_partial[b*NW+i];
    float ent = ep * (1.f/(NW*512.f));
    float lg[8];
    #pragma unroll
    for (int e=0;e<8;e++)
      lg[e] = accs[0][lane][e]+accs[1][lane][e]+accs[2][lane][e]+accs[3][lane][e];
    float invT = 1.f/(fabsf(temp[0])+1e-6f);
    #pragma unroll
    for (int e=0;e<8;e++) lg[e] = (lg[e] + ent*entw[e] + entb[e]) * invT;
    int i0=0; float v0=lg[0];
    #pragma unroll
    for (int e=1;e<8;e++) if (lg[e] > v0){ v0=lg[e]; i0=e; }
    int i1=-1; float v1=-1e30f;
    #pragma unroll
    for (int e=0;e<8;e++) if (e!=i0 && lg[e] > v1){ v1=lg[e]; i1=e; }
    float e1 = expf(v1-v0);
    float rw0 = 1.f/(1.f+e1), rw1 = e1/(1.f+e1);
    float pr[8], se=0.f;
    #pragma unroll
    for (int e=0;e<8;e++){ pr[e]=expf(lg[e]-v0); se+=pr[e]; }
    float ise = 1.f/se;
    #pragma unroll
    for (int e=0;e<8;e++) wfull[(size_t)r*8+e] = (e==i0)?rw0 : ((e==i1)?rw1 : 0.f);
    atomicAdd(&l_tpe[i0],1.f); atomicAdd(&l_tpe[i1],1.f);
    #pragma unroll
    for (int e=0;e<8;e++) atomicAdd(&l_avg[e], pr[e]*ise);
  }
  __syncthreads();
  if (tid < 8){ atomicAdd(&g_tpe[tid], l_tpe[tid]); atomicAdd(&g_avg[tid], l_avg[tid]); }
}

__global__ void aux_kernel(const float* __restrict__ g_tpe, const float* __restrict__ g_avg,
                           float* __restrict__ out)
{
  float a=0.f;
  #pragma unroll
  for (int e=0;e<8;e++) a += (g_tpe[e]*(1.f/BT_)) * (g_avg[e]*(1.f/BT_));
  out[(size_t)BT_*DM] = 8.f*a;
}

// ---------------- depthwise causal convs (8 channels / thread) ----------------
__global__ __launch_bounds__(256)
void dwconv7_gelu(const unsigned short* __restrict__ H1, const float* __restrict__ k7,
                  const float* __restrict__ kb, unsigned short* __restrict__ H2)
{
  size_t gid = (size_t)blockIdx.x*256 + threadIdx.x;
  int dg = (int)(gid & 127);
  size_t row = gid >> 7;
  int t = (int)(row & (Tt-1));
  int d0 = dg*8;
  float acc[8];
  #pragma unroll
  for (int i=0;i<8;i++) acc[i] = kb[d0+i];
  #pragma unroll
  for (int j=0;j<7;j++){
    int off = 6-j;
    if (t - off >= 0){
      union { uint4 v; unsigned short s[8]; } u;
      u.v = *(const uint4*)(H1 + (row-(size_t)off)*DIN_ + d0);
      #pragma unroll
      for (int i=0;i<8;i++) acc[i] += bf2f(u.s[i]) * k7[(size_t)(d0+i)*7+j];
    }
  }
  union { uint4 v; unsigned short s[8]; } o;
  #pragma unroll
  for (int i=0;i<8;i++) o.s[i] = f2bf(gelu_f(acc[i]));
  *(uint4*)(H2 + row*DIN_ + d0) = o.v;
}

__global__ __launch_bounds__(256)
void dwconv4_silu(const unsigned short* __restrict__ U, const float* __restrict__ cw,
                  const float* __restrict__ cb, unsigned short* __restrict__ uH)
{
  size_t gid = (size_t)blockIdx.x*256 + threadIdx.x;
  int dg = (int)(gid & 127);
  size_t row = gid >> 7;
  int t = (int)(row & (Tt-1));
  int d0 = dg*8;
  float acc[8];
  #pragma unroll
  for (int i=0;i<8;i++) acc[i] = cb[d0+i];
  #pragma unroll
  for (int j=0;j<4;j++){
    int off = 3-j;
    if (t - off >= 0){
      union { uint4 v; unsigned short s[8]; } u;
      u.v = *(const uint4*)(U + (row-(size_t)off)*DIN_ + d0);
      #pragma unroll
      for (int i=0;i<8;i++) acc[i] += bf2f(u.s[i]) * cw[(size_t)(d0+i)*4+j];
    }
  }
  union { uint4 v; unsigned short s[8]; } o;
  #pragma unroll
  for (int i=0;i<8;i++){ float v = acc[i]; o.s[i] = f2bf(v/(1.f+expf(-v))); }
  *(uint4*)(uH + row*DIN_ + d0) = o.v;
}

// ---------------- chunk-parallel selective scan with fused delta (128-step chunks) ----------------
__global__ __launch_bounds__(256)
void scan_k(const float* __restrict__ dbc, const unsigned short* __restrict__ uH,
            const unsigned short* __restrict__ zH,
            const float* __restrict__ dtw, const float* __restrict__ dtb,
            const float* __restrict__ Alog, const float* __restrict__ Dp,
            unsigned short* __restrict__ yH)
{
  int tid = threadIdx.x;
  int blk = blockIdx.x;
  int dblk = blk & 3, chunk = (blk>>2) & 31, b = blk>>7;
  int d = dblk*256 + tid;
  int t0 = chunk*128, t1 = t0+128;
  int t = (t0 >= 64) ? t0-64 : 0;
  float wk[32];
  #pragma unroll
  for (int k=0;k<32;k++) wk[k] = dtw[(size_t)k*DIN_ + d];
  float dtbv = dtb[d];
  float As[DSTATE_];
  bool fastb = true;
  #pragma unroll
  for (int s=0;s<DSTATE_;s++){
    As[s] = -expf(Alog[(size_t)d*DSTATE_+s]);
    if (fabsf(As[s] + (float)(s+1)) > 1e-3f) fastb=false;
  }
  int fast = __all((int)fastb);
  float Dv = Dp[d];
  float h[DSTATE_];
  #pragma unroll
  for (int s=0;s<DSTATE_;s++) h[s]=0.f;
  for (; t<t1; ++t){
    size_t row = ((size_t)b<<12) + t;
    const float* rowp = dbc + row*128;
    float p0=0.f,p1=0.f,p2=0.f,p3=0.f;
    #pragma unroll
    for (int k=0;k<32;k+=4){
      p0 += rowp[k]*wk[k];   p1 += rowp[k+1]*wk[k+1];
      p2 += rowp[k+2]*wk[k+2]; p3 += rowp[k+3]*wk[k+3];
    }
    float s0 = dtbv + ((p0+p1)+(p2+p3));
    float dl = (s0 > 20.f) ? s0 : log1pf(expf(s0));
    float u  = bf2f(uH[row*DIN_+d]);
    float Bv[DSTATE_], Cv[DSTATE_];
    const float4* pb = (const float4*)(rowp + 32);
    const float4* pc = (const float4*)(rowp + 48);
    #pragma unroll
    for (int q=0;q<4;q++){
      float4 fb_ = pb[q]; Bv[4*q]=fb_.x; Bv[4*q+1]=fb_.y; Bv[4*q+2]=fb_.z; Bv[4*q+3]=fb_.w;
      float4 fc_ = pc[q]; Cv[4*q]=fc_.x; Cv[4*q+1]=fc_.y; Cv[4*q+2]=fc_.z; Cv[4*q+3]=fc_.w;
    }
    float du = dl*u;
    if (fast){
      float e1 = __expf(-dl);
      float pw = e1;
      #pragma unroll
      for (int s=0;s<DSTATE_;s++){ h[s] = pw*h[s] + du*Bv[s]; pw *= e1; }
    } else {
      #pragma unroll
      for (int s=0;s<DSTATE_;s++){ float a = __expf(dl*As[s]); h[s] = a*h[s] + du*Bv[s]; }
    }
    if (t >= t0){
      float y = 0.f;
      #pragma unroll
      for (int s=0;s<DSTATE_;s++) y += h[s]*Cv[s];
      y += u*Dv;
      float z = bf2f(zH[row*DIN_+d]);
      float sil = z/(1.f+expf(-z));
      yH[row*DIN_+d] = f2bf(y*sil);
    }
  }
}

// ---------------- bf16 MFMA GEMM, 128x128 tile, BK=64, reg-staged padded LDS ----------------
enum { E_GELU_BF16=0, E_BF16=1, E_F32=2, E_MOE=3 };

template<int EPI>
__global__ __launch_bounds__(256,2)
void gemm_k(const unsigned short* __restrict__ A, int lda,
            const unsigned short* __restrict__ Bm, int ldb,
            int K,
            const float* __restrict__ bias,
            float* __restrict__ oF, unsigned short* __restrict__ oH, int ldo,
            const float* __restrict__ wfull, int ecol,
            const float* __restrict__ resid,
            unsigned short* __restrict__ oH2)
{
  __shared__ unsigned short As[128*72];
  __shared__ unsigned short Bs[128*72];
  int tid = threadIdx.x, lane = tid&63, wv = tid>>6;
  int wm = wv>>1, wn = wv&1;
  int nwg = gridDim.x*gridDim.y;
  int wg  = blockIdx.y*gridDim.x + blockIdx.x;
  int cpx = nwg >> 3;
  int swz = (wg & 7)*cpx + (wg >> 3);
  int bx = swz % gridDim.x, by = swz / gridDim.x;
  int mb = by*128, nb = bx*128;
  int g4 = (lane>>4)<<2;
  int r16 = lane & 15;
  f32x4 acc[4][4];
  #pragma unroll
  for (int i=0;i<4;i++)
    #pragma unroll
    for (int j=0;j<4;j++) acc[i][j] = (f32x4){0.f,0.f,0.f,0.f};

  for (int k0=0; k0<K; k0+=64) {
    #pragma unroll
    for (int i=0;i<4;i++){
      int c  = tid + (i<<8);
      int r  = c>>3, ko = (c&7)<<3;
      uint4 va = *(const uint4*)(A  + (size_t)(mb+r)*lda + k0+ko);
      uint4 vb = *(const uint4*)(Bm + (size_t)(nb+r)*ldb + k0+ko);
      *(uint4*)&As[r*72+ko] = va;
      *(uint4*)&Bs[r*72+ko] = vb;
    }
    __syncthreads();
    #pragma unroll
    for (int ks=0; ks<2; ks++){
      int kb = ks<<5;
      s16x8 fa[4], fb[4];
      #pragma unroll
      for (int mi=0;mi<4;mi++){
        const unsigned short* p = &As[(wm*64+mi*16+r16)*72 + kb + g4];
        union { uint64_t q[2]; s16x8 v; } u;
        u.q[0] = *(const uint64_t*)p;
        u.q[1] = *(const uint64_t*)(p+16);
        fa[mi] = u.v;
      }
      #pragma unroll
      for (int ni=0;ni<4;ni++){
        const unsigned short* p = &Bs[(wn*64+ni*16+r16)*72 + kb + g4];
        union { uint64_t q[2]; s16x8 v; } u;
        u.q[0] = *(const uint64_t*)p;
        u.q[1] = *(const uint64_t*)(p+16);
        fb[ni] = u.v;
      }
      #pragma unroll
      for (int mi=0;mi<4;mi++)
        #pragma unroll
        for (int ni=0;ni<4;ni++)
          acc[mi][ni] = __builtin_amdgcn_mfma_f32_16x16x32_bf16(fa[mi], fb[ni], acc[mi][ni], 0,0,0);
    }
    __syncthreads();
  }
  #pragma unroll
  for (int mi=0;mi<4;mi++){
    #pragma unroll
    for (int ni=0;ni<4;ni++){
      #pragma unroll
      for (int rr=0;rr<4;rr++){
        int row = mb + wm*64 + mi*16 + g4 + rr;
        int col = nb + wn*64 + ni*16 + r16;
        float v = acc[mi][ni][rr];
        if constexpr (EPI == E_GELU_BF16){
          v += bias[col];
          oH[(size_t)row*ldo + col] = f2bf(gelu_f(v));
        } else if constexpr (EPI == E_BF16){
          if (bias) v += bias[col];
          if (oH2 && col >= 1024) oH2[(size_t)row*1024 + col - 1024] = f2bf(v);
          else                    oH [(size_t)row*ldo  + col] = f2bf(v);
        } else if constexpr (EPI == E_F32){
          oF[(size_t)row*ldo + col] = v;
        } else { // E_MOE
          size_t o = (size_t)row*ldo + col;
          if (bias) v += bias[col];
          float w = wfull[(size_t)row*8 + ecol];
          float base = resid ? resid[o] : oF[o];
          oF[o] = base + w*v;
        }
      }
    }
  }
}

extern "C" void kernel_launch(void* const* d_in, const int* in_sizes, int n_in,
                              void* d_out, int out_size, void* d_ws, size_t ws_size,
                              hipStream_t stream)
{
  (void)in_sizes; (void)n_in; (void)out_size;
  const float* x      = (const float*)d_in[0];
  const float* ln_g   = (const float*)d_in[1];
  const float* ln_b   = (const float*)d_in[2];
  const float* gate_w = (const float*)d_in[3];
  const float* ent_w  = (const float*)d_in[4];
  const float* ent_b  = (const float*)d_in[5];
  const float* temp   = (const float*)d_in[6];
  const float* cin_w  = (const float*)d_in[7];
  const float* cin_b  = (const float*)d_in[8];
  const float* ck     = (const float*)d_in[9];
  const float* ck_b   = (const float*)d_in[10];
  const float* cout_w = (const float*)d_in[11];
  const float* cout_b = (const float*)d_in[12];
  const float* m_in   = (const float*)d_in[13];
  const float* m_cw   = (const float*)d_in[14];
  const float* m_cb   = (const float*)d_in[15];
  const float* m_xp   = (const float*)d_in[16];
  const float* m_dtw  = (const float*)d_in[17];
  const float* m_dtb  = (const float*)d_in[18];
  const float* m_alog = (const float*)d_in[19];
  const float* m_Dd   = (const float*)d_in[20];
  const float* m_op   = (const float*)d_in[21];
  float* out = (float*)d_out;
  char* ws = (char*)d_ws;

  size_t off = 0;
  auto alloc = [&](size_t bytes)->size_t{
    size_t r = off; off += (bytes + 4095) & ~(size_t)4095; return r;
  };
  size_t o_xnH  = alloc((size_t)BT_*DM*2);
  size_t o_wf   = alloc((size_t)BT_*8*4);
  size_t o_st   = alloc(4096);
  size_t o_wCI  = alloc((size_t)4*DIN_*DM*2);
  size_t o_wCO  = alloc((size_t)4*DM*DIN_*2);
  size_t o_wIP  = alloc((size_t)4*2048*DM*2);
  size_t o_wXP  = alloc((size_t)4*128*DIN_*2);
  size_t o_wOP  = alloc((size_t)4*DM*DIN_*2);
  size_t o_A0   = alloc((size_t)BT_*DIN_*2);   // u_raw / conv H1 / y   | dftO (with A1)
  size_t o_A1   = alloc((size_t)BT_*DIN_*2);   // z                     | dftO tail
  size_t o_A3   = alloc((size_t)BT_*DIN_*2);   // u' / conv H2          | xnTH (bf16 T)
  size_t o_A4   = alloc((size_t)BT_*128*4);    // dbc f32               | dftW + rowent
  size_t o_xnT  = alloc((size_t)BT_*DM*4);     // f32 xn transposed (DM, BT)
  size_t need = off;

  if (ws_size < need){
    diag_k<<<1,1,0,stream>>>(out, (float)(ws_size >> 20));
    return;
  }

  unsigned short* xnH  = (unsigned short*)(ws + o_xnH);
  float*          xnT  = (float*)(ws + o_xnT);
  float*          wfull= (float*)(ws + o_wf);
  float*          entP = (float*)(ws + o_st);
  float*          gtpe = (float*)(ws + o_st + 512);
  float*          gavg = (float*)(ws + o_st + 544);
  unsigned short* wtCI = (unsigned short*)(ws + o_wCI);
  unsigned short* wtCO = (unsigned short*)(ws + o_wCO);
  unsigned short* wtIP = (unsigned short*)(ws + o_wIP);
  unsigned short* wtXP = (unsigned short*)(ws + o_wXP);
  unsigned short* wtOP = (unsigned short*)(ws + o_wOP);
  unsigned short* a0H  = (unsigned short*)(ws + o_A0);
  unsigned short* a1H  = (unsigned short*)(ws + o_A1);
  unsigned short* a3H  = (unsigned short*)(ws + o_A3);
  float*          a4F  = (float*)(ws + o_A4);
  // entropy-phase aliases (used only before experts run)
  float*          dftO   = (float*)(ws + o_A0);              // 63488*256*4 = 65 MB < A0+A1
  unsigned short* xnTH   = (unsigned short*)(ws + o_A3);     // 16.8 MB < 33.5 MB
  unsigned short* dftW   = (unsigned short*)(ws + o_A4);     // 128 KB
  float*          rowent = (float*)(ws + o_A4 + (512<<10));  // 254 KB, after dftW

  hipMemsetAsync(ws + o_st, 0, 4096, stream);

  transpose_cvt<<<dim3(32,16,4),256,0,stream>>>(cin_w,  wtCI, 512, 1024, 1024);
  transpose_cvt<<<dim3(16,32,4),256,0,stream>>>(cout_w, wtCO, 1024, 512, 512);
  transpose_cvt<<<dim3(64,16,4),256,0,stream>>>(m_in,   wtIP, 512, 2048, 2048);
  transpose_cvt<<<dim3( 4,32,4),256,0,stream>>>(m_xp,   wtXP, 1024, 64, 128);
  transpose_cvt<<<dim3(16,32,4),256,0,stream>>>(m_op,   wtOP, 1024, 512, 512);
  dft_init<<<256,256,0,stream>>>(dftW);

  ln_kernel<<<BT_/64,256,0,stream>>>(x, ln_g, ln_b, xnT, xnTH, xnH);
  dft_gemm<<<dim3(2, NWIN*4),256,0,stream>>>(xnTH, dftW, dftO);
  ent_reduce<<<NWIN*512/4,256,0,stream>>>(dftO, xnTH, rowent);
  ent_stage2<<<NWIN,256,0,stream>>>(rowent, entP);
  gating_kernel<<<BT_/64,256,0,stream>>>(xnT, gate_w, ent_w, ent_b, temp, entP, wfull, gtpe, gavg);

  // conv experts (0..3)
  for (int e=0;e<4;e++){
    gemm_k<E_GELU_BF16><<<dim3(8,128),256,0,stream>>>(
        xnH, DM, wtCI + (size_t)e*DIN_*DM, DM, DM,
        cin_b + (size_t)e*DIN_, nullptr, a0H, DIN_, nullptr, 0, nullptr, nullptr);
    dwconv7_gelu<<<BT_*DIN_/8/256,256,0,stream>>>(a0H, ck + (size_t)e*DIN_*7, ck_b + (size_t)e*DIN_, a3H);
    gemm_k<E_MOE><<<dim3(4,128),256,0,stream>>>(
        a3H, DIN_, wtCO + (size_t)e*DM*DIN_, DIN_, DIN_,
        cout_b + (size_t)e*DM, out, nullptr, DM, wfull, e, (e==0)? x : nullptr, nullptr);
  }

  // mamba experts (4..7)
  for (int e=0;e<4;e++){
    gemm_k<E_BF16><<<dim3(16,128),256,0,stream>>>(
        xnH, DM, wtIP + (size_t)e*2048*DM, DM, DM,
        nullptr, nullptr, a0H, DIN_, nullptr, 0, nullptr, a1H);            // u_raw + z split
    dwconv4_silu<<<BT_*DIN_/8/256,256,0,stream>>>(a0H, m_cw + (size_t)e*DIN_*4, m_cb + (size_t)e*DIN_, a3H);
    gemm_k<E_F32><<<dim3(1,128),256,0,stream>>>(
        a3H, DIN_, wtXP + (size_t)e*128*DIN_, DIN_, DIN_,
        nullptr, a4F, nullptr, 128, nullptr, 0, nullptr, nullptr);         // dbc
    scan_k<<<512,256,0,stream>>>(a4F, a3H, a1H,
        m_dtw + (size_t)e*32*DIN_, m_dtb + (size_t)e*DIN_,
        m_alog + (size_t)e*DIN_*DSTATE_, m_Dd + (size_t)e*DIN_, a0H);      // y -> a0H
    gemm_k<E_MOE><<<dim3(4,128),256,0,stream>>>(
        a0H, DIN_, wtOP + (size_t)e*DM*DIN_, DIN_, DIN_,
        nullptr, out, nullptr, DM, wfull, 4+e, nullptr, nullptr);
  }

  aux_kernel<<<1,1,0,stream>>>(gtpe, gavg, out);
}

// Round 9
// 3130.822 us; speedup vs baseline: 1.2915x; 1.1691x over previous
//
#include <hip/hip_runtime.h>
#include <stdint.h>

// ---------------- problem constants ----------------
#define Bb    4
#define Tt    4096
#define DM    512
#define DIN_  1024
#define BT_   16384        // Bb*Tt
#define NW    31           // entropy windows: (4096-256)/128+1
#define DSTATE_ 16
#define NWIN  124          // Bb*NW

typedef float f32x4 __attribute__((ext_vector_type(4)));
typedef short s16x8 __attribute__((ext_vector_type(8)));

static __device__ __forceinline__ float bf2f(unsigned short h){
  union { unsigned int u; float f; } v; v.u = ((unsigned int)h)<<16; return v.f;
}
static __device__ __forceinline__ unsigned short f2bf(float f){
  union { float f; unsigned int u; } v; v.f = f;
  unsigned int u = v.u + 0x7fffu + ((v.u>>16)&1u);   // RTNE
  return (unsigned short)(u>>16);
}
static __device__ __forceinline__ float gelu_f(float x){
  return 0.5f*x*(1.0f+erff(x*0.7071067811865476f));
}

__global__ void diag_k(float* out, float v){ out[0] = v; }

// ---------------- LayerNorm: 64-token tiles -> xnT (f32 T) + xnTH (bf16 T) + xnH (bf16 row) ----------------
__global__ __launch_bounds__(256)
void ln_kernel(const float* __restrict__ x, const float* __restrict__ g,
               const float* __restrict__ be, float* __restrict__ xnT,
               unsigned short* __restrict__ xnTH, unsigned short* __restrict__ xnH)
{
  __shared__ float mrs[64][2];
  __shared__ __align__(16) float tile[64][33];
  int tid = threadIdx.x, lane = tid&63, wv = tid>>6;
  int r0 = blockIdx.x*64;
  for (int j=0;j<16;j++){
    int r = r0 + wv*16 + j;
    const float4* px = (const float4*)(x + (size_t)r*DM);
    float4 a = px[lane*2], b4 = px[lane*2+1];
    float s1 = a.x+a.y+a.z+a.w + b4.x+b4.y+b4.z+b4.w;
    float s2 = a.x*a.x+a.y*a.y+a.z*a.z+a.w*a.w + b4.x*b4.x+b4.y*b4.y+b4.z*b4.z+b4.w*b4.w;
    #pragma unroll
    for (int o=32;o>=1;o>>=1){ s1 += __shfl_xor(s1,o); s2 += __shfl_xor(s2,o); }
    if (lane==0){
      float m = s1*(1.f/DM);
      float var = s2*(1.f/DM) - m*m;
      mrs[wv*16+j][0] = m;
      mrs[wv*16+j][1] = rsqrtf(var + 1e-5f);
    }
  }
  __syncthreads();
  for (int d0=0; d0<DM; d0+=32){
    #pragma unroll
    for (int q=0;q<8;q++){
      int tk = q*8 + (tid>>5);
      int dj = tid & 31;
      int r = r0+tk, d = d0+dj;
      float v = x[(size_t)r*DM + d];
      float nv = (v - mrs[tk][0])*mrs[tk][1]*g[d] + be[d];
      tile[tk][dj] = nv;
      xnH[(size_t)r*DM + d] = f2bf(nv);
    }
    __syncthreads();
    #pragma unroll
    for (int q=0;q<8;q++){
      int dj = q*4 + (tid>>6);
      int tk = tid & 63;
      float v = tile[tk][dj];
      xnT [(size_t)(d0+dj)*BT_ + r0 + tk] = v;
      xnTH[(size_t)(d0+dj)*BT_ + r0 + tk] = f2bf(v);
    }
    __syncthreads();
  }
}

// ---------------- weight transpose + f32->bf16: (E,K,N) -> (E,Npad,K-stride Kpad) ----------------
__global__ __launch_bounds__(256)
void transpose_cvt(const float* __restrict__ src, unsigned short* __restrict__ dst,
                   int K, int N, int Npad, int Kpad)
{
  __shared__ float tile[32][33];
  int e = blockIdx.z;
  int n0 = blockIdx.x<<5, k0 = blockIdx.y<<5;
  int tx = threadIdx.x & 31, ty = threadIdx.x >> 5;
  #pragma unroll
  for (int i=0;i<4;i++){
    int k = k0 + ty + i*8, n = n0 + tx;
    float v = (n < N) ? src[((size_t)e*K + k)*N + n] : 0.f;
    tile[ty+i*8][tx] = v;
  }
  __syncthreads();
  #pragma unroll
  for (int i=0;i<4;i++){
    int n = n0 + ty + i*8, k = k0 + tx;
    if (n < Npad) dst[((size_t)e*Npad + n)*Kpad + k] = f2bf(tile[tx][ty+i*8]);
  }
}

// ---------------- DFT weight matrix ----------------
__global__ void dft_init(unsigned short* __restrict__ w)
{
  int n = blockIdx.x, k = threadIdx.x;
  int bin = (n < 128) ? n+1 : n-127;
  int idx = (bin*k) & 255;                    // exact integer angle reduction
  float ang = 6.283185307179586f * (float)idx / 256.f;
  float sv, cv; sincosf(ang, &sv, &cv);
  w[n*256 + k] = f2bf((n < 128) ? cv : sv);
}

// ---------------- DFT GEMM: per (window, d-block) 128x128x256 bf16 MFMA ----------------
__global__ __launch_bounds__(256,2)
void dft_gemm(const unsigned short* __restrict__ xnTH, const unsigned short* __restrict__ dftW,
              float* __restrict__ dftO)
{
  __shared__ unsigned short As[128*72];
  __shared__ unsigned short Bs[128*72];
  int tid = threadIdx.x, lane = tid&63, wv = tid>>6;
  int wm = wv>>1, wn = wv&1;
  int win = blockIdx.y >> 2, dblk = blockIdx.y & 3;
  int woff = (win/NW)*Tt + (win%NW)*128;
  int mb = dblk*128;
  int nb = blockIdx.x*128;
  int g4 = (lane>>4)<<2;
  int r16 = lane & 15;
  f32x4 acc[4][4];
  #pragma unroll
  for (int i=0;i<4;i++)
    #pragma unroll
    for (int j=0;j<4;j++) acc[i][j] = (f32x4){0.f,0.f,0.f,0.f};

  for (int k0=0; k0<256; k0+=64) {
    #pragma unroll
    for (int i=0;i<4;i++){
      int c  = tid + (i<<8);
      int r  = c>>3, ko = (c&7)<<3;
      uint4 va = *(const uint4*)(xnTH + (size_t)(mb+r)*BT_ + woff + k0+ko);
      uint4 vb = *(const uint4*)(dftW + (size_t)(nb+r)*256 + k0+ko);
      *(uint4*)&As[r*72+ko] = va;
      *(uint4*)&Bs[r*72+ko] = vb;
    }
    __syncthreads();
    #pragma unroll
    for (int ks=0; ks<2; ks++){
      int kb = ks<<5;
      s16x8 fa[4], fb[4];
      #pragma unroll
      for (int mi=0;mi<4;mi++){
        const unsigned short* p = &As[(wm*64+mi*16+r16)*72 + kb + g4];
        union { uint64_t q[2]; s16x8 v; } u;
        u.q[0] = *(const uint64_t*)p;
        u.q[1] = *(const uint64_t*)(p+16);
        fa[mi] = u.v;
      }
      #pragma unroll
      for (int ni=0;ni<4;ni++){
        const unsigned short* p = &Bs[(wn*64+ni*16+r16)*72 + kb + g4];
        union { uint64_t q[2]; s16x8 v; } u;
        u.q[0] = *(const uint64_t*)p;
        u.q[1] = *(const uint64_t*)(p+16);
        fb[ni] = u.v;
      }
      #pragma unroll
      for (int mi=0;mi<4;mi++)
        #pragma unroll
        for (int ni=0;ni<4;ni++)
          acc[mi][ni] = __builtin_amdgcn_mfma_f32_16x16x32_bf16(fa[mi], fb[ni], acc[mi][ni], 0,0,0);
    }
    __syncthreads();
  }
  #pragma unroll
  for (int mi=0;mi<4;mi++){
    #pragma unroll
    for (int ni=0;ni<4;ni++){
      #pragma unroll
      for (int rr=0;rr<4;rr++){
        int row = win*512 + mb + wm*64 + mi*16 + g4 + rr;
        int col = nb + wn*64 + ni*16 + r16;
        dftO[(size_t)row*256 + col] = acc[mi][ni][rr];
      }
    }
  }
}

// ---------------- entropy reduce stage 1: one wave per (window,d) row, NO atomics ----------------
__global__ __launch_bounds__(256)
void ent_reduce(const float* __restrict__ dftO, const unsigned short* __restrict__ xnTH,
                float* __restrict__ rowent)
{
  int tid = threadIdx.x, lane = tid&63, wv = tid>>6;
  int row = blockIdx.x*4 + wv;            // 0..63487
  int win = row >> 9, d = row & 511;
  int b = win / NW, w = win - b*NW;
  size_t sb = (size_t)d*BT_ + (size_t)b*Tt + (size_t)w*128;
  union { uint64_t q; unsigned short s[4]; } u;
  u.q = *(const uint64_t*)(xnTH + sb + lane*4);
  float lsum = bf2f(u.s[0])+bf2f(u.s[1])+bf2f(u.s[2])+bf2f(u.s[3]);
  #pragma unroll
  for (int o=32;o>=1;o>>=1) lsum += __shfl_xor(lsum,o);
  const float* r = dftO + (size_t)row*256;
  float c1 = r[lane], c2 = r[64+lane], s1 = r[128+lane], s2 = r[192+lane];
  float m1 = sqrtf(c1*c1+s1*s1) + 1e-10f;
  float m2 = sqrtf(c2*c2+s2*s2) + 1e-10f;
  float m0 = fabsf(lsum) + 1e-10f;
  float ps = m1 + m2 + ((lane==0)? m0 : 0.f);
  #pragma unroll
  for (int o=32;o>=1;o>>=1) ps += __shfl_xor(ps,o);
  float inv = 1.f/ps;
  float p1 = m1*inv, p2 = m2*inv;
  float es = -p1*logf(p1+1e-10f) - p2*logf(p2+1e-10f);
  if (lane==0){ float p0 = m0*inv; es -= p0*logf(p0+1e-10f); }
  #pragma unroll
  for (int o=32;o>=1;o>>=1) es += __shfl_xor(es,o);
  if (lane==0) rowent[row] = es*(1.f/4.859812404361672f);   // /ln(129)
}

// ---------------- entropy reduce stage 2 ----------------
__global__ __launch_bounds__(256)
void ent_stage2(const float* __restrict__ rowent, float* __restrict__ entP)
{
  __shared__ float r4[4];
  int win = blockIdx.x, tid = threadIdx.x, lane = tid&63, wv = tid>>6;
  const float* p = rowent + (size_t)win*512;
  float s = p[tid] + p[tid+256];
  #pragma unroll
  for (int o=32;o>=1;o>>=1) s += __shfl_xor(s,o);
  if (lane==0) r4[wv] = s;
  __syncthreads();
  if (tid==0) entP[win] = r4[0]+r4[1]+r4[2]+r4[3];
}

// ---------------- gating: 64-token tiles, coalesced xnT reads ----------------
__global__ __launch_bounds__(256)
void gating_kernel(const float* __restrict__ xnT, const float* __restrict__ gw,
                   const float* __restrict__ entw, const float* __restrict__ entb,
                   const float* __restrict__ temp, const float* __restrict__ ent_partial,
                   float* __restrict__ wfull, float* __restrict__ g_tpe, float* __restrict__ g_avg)
{
  __shared__ __align__(16) float accs[4][64][8];
  __shared__ float l_tpe[8], l_avg[8];
  int tid = threadIdx.x, lane = tid&63, wv = tid>>6;
  int r0 = blockIdx.x*64;
  if (tid < 8){ l_tpe[tid]=0.f; l_avg[tid]=0.f; }
  float acc[8];
  #pragma unroll
  for (int e=0;e<8;e++) acc[e]=0.f;
  for (int i=0;i<128;i++){
    int dd = wv*128 + i;
    float xv = xnT[(size_t)dd*BT_ + r0 + lane];
    const float4* g4p = (const float4*)(gw + (size_t)dd*8);
    float4 w0 = g4p[0], w1 = g4p[1];
    acc[0]+=xv*w0.x; acc[1]+=xv*w0.y; acc[2]+=xv*w0.z; acc[3]+=xv*w0.w;
    acc[4]+=xv*w1.x; acc[5]+=xv*w1.y; acc[6]+=xv*w1.z; acc[7]+=xv*w1.w;
  }
  #pragma unroll
  for (int e=0;e<8;e++) accs[wv][lane][e] = acc[e];
  __syncthreads();
  if (wv==0){
    int r = r0 + lane;
    int b = r0 >> 12;
    float ep = 0.f;
    for (int i=0;i<NW;i++) ep += ent_partial[b*NW+i];
    float ent = ep * (1.f/(NW*512.f));
    float lg[8];
    #pragma unroll
    for (int e=0;e<8;e++)
      lg[e] = accs[0][lane][e]+accs[1][lane][e]+accs[2][lane][e]+accs[3][lane][e];
    float invT = 1.f/(fabsf(temp[0])+1e-6f);
    #pragma unroll
    for (int e=0;e<8;e++) lg[e] = (lg[e] + ent*entw[e] + entb[e]) * invT;
    int i0=0; float v0=lg[0];
    #pragma unroll
    for (int e=1;e<8;e++) if (lg[e] > v0){ v0=lg[e]; i0=e; }
    int i1=-1; float v1=-1e30f;
    #pragma unroll
    for (int e=0;e<8;e++) if (e!=i0 && lg[e] > v1){ v1=lg[e]; i1=e; }
    float e1 = expf(v1-v0);
    float rw0 = 1.f/(1.f+e1), rw1 = e1/(1.f+e1);
    float pr[8], se=0.f;
    #pragma unroll
    for (int e=0;e<8;e++){ pr[e]=expf(lg[e]-v0); se+=pr[e]; }
    float ise = 1.f/se;
    #pragma unroll
    for (int e=0;e<8;e++) wfull[(size_t)r*8+e] = (e==i0)?rw0 : ((e==i1)?rw1 : 0.f);
    atomicAdd(&l_tpe[i0],1.f); atomicAdd(&l_tpe[i1],1.f);
    #pragma unroll
    for (int e=0;e<8;e++) atomicAdd(&l_avg[e], pr[e]*ise);
  }
  __syncthreads();
  if (tid < 8){ atomicAdd(&g_tpe[tid], l_tpe[tid]); atomicAdd(&g_avg[tid], l_avg[tid]); }
}

__global__ void aux_kernel(const float* __restrict__ g_tpe, const float* __restrict__ g_avg,
                           float* __restrict__ out)
{
  float a=0.f;
  #pragma unroll
  for (int e=0;e<8;e++) a += (g_tpe[e]*(1.f/BT_)) * (g_avg[e]*(1.f/BT_));
  out[(size_t)BT_*DM] = 8.f*a;
}

// ---------------- depthwise causal convs (8 channels / thread) ----------------
__global__ __launch_bounds__(256)
void dwconv7_gelu(const unsigned short* __restrict__ H1, const float* __restrict__ k7,
                  const float* __restrict__ kb, unsigned short* __restrict__ H2)
{
  size_t gid = (size_t)blockIdx.x*256 + threadIdx.x;
  int dg = (int)(gid & 127);
  size_t row = gid >> 7;
  int t = (int)(row & (Tt-1));
  int d0 = dg*8;
  float acc[8];
  #pragma unroll
  for (int i=0;i<8;i++) acc[i] = kb[d0+i];
  #pragma unroll
  for (int j=0;j<7;j++){
    int off = 6-j;
    if (t - off >= 0){
      union { uint4 v; unsigned short s[8]; } u;
      u.v = *(const uint4*)(H1 + (row-(size_t)off)*DIN_ + d0);
      #pragma unroll
      for (int i=0;i<8;i++) acc[i] += bf2f(u.s[i]) * k7[(size_t)(d0+i)*7+j];
    }
  }
  union { uint4 v; unsigned short s[8]; } o;
  #pragma unroll
  for (int i=0;i<8;i++) o.s[i] = f2bf(gelu_f(acc[i]));
  *(uint4*)(H2 + row*DIN_ + d0) = o.v;
}

__global__ __launch_bounds__(256)
void dwconv4_silu(const unsigned short* __restrict__ U, const float* __restrict__ cw,
                  const float* __restrict__ cb, unsigned short* __restrict__ uH)
{
  size_t gid = (size_t)blockIdx.x*256 + threadIdx.x;
  int dg = (int)(gid & 127);
  size_t row = gid >> 7;
  int t = (int)(row & (Tt-1));
  int d0 = dg*8;
  float acc[8];
  #pragma unroll
  for (int i=0;i<8;i++) acc[i] = cb[d0+i];
  #pragma unroll
  for (int j=0;j<4;j++){
    int off = 3-j;
    if (t - off >= 0){
      union { uint4 v; unsigned short s[8]; } u;
      u.v = *(const uint4*)(U + (row-(size_t)off)*DIN_ + d0);
      #pragma unroll
      for (int i=0;i<8;i++) acc[i] += bf2f(u.s[i]) * cw[(size_t)(d0+i)*4+j];
    }
  }
  union { uint4 v; unsigned short s[8]; } o;
  #pragma unroll
  for (int i=0;i<8;i++){ float v = acc[i]; o.s[i] = f2bf(v/(1.f+expf(-v))); }
  *(uint4*)(uH + row*DIN_ + d0) = o.v;
}

// ---------------- chunk-parallel selective scan: precomputed delta, 64-step chunks ----------------
__global__ __launch_bounds__(256)
void scan_k(const float* __restrict__ dbc, const unsigned short* __restrict__ dlH,
            const unsigned short* __restrict__ uH, const unsigned short* __restrict__ zH,
            const float* __restrict__ Alog, const float* __restrict__ Dp,
            unsigned short* __restrict__ yH)
{
  int tid = threadIdx.x;
  int blk = blockIdx.x;
  int dblk = blk & 3, chunk = (blk>>2) & 63, b = blk>>8;
  int d = dblk*256 + tid;
  int t0 = chunk*64, t1 = t0+64;
  int t = (t0 >= 64) ? t0-64 : 0;     // warmup: decay <= e^-38 typ, negligible
  float As[DSTATE_];
  bool fastb = true;
  #pragma unroll
  for (int s=0;s<DSTATE_;s++){
    As[s] = -expf(Alog[(size_t)d*DSTATE_+s]);
    if (fabsf(As[s] + (float)(s+1)) > 1e-3f) fastb=false;
  }
  int fast = __all((int)fastb);
  float Dv = Dp[d];
  float h[DSTATE_];
  #pragma unroll
  for (int s=0;s<DSTATE_;s++) h[s]=0.f;
  for (; t<t1; ++t){
    size_t row = ((size_t)b<<12) + t;
    const float* rowp = dbc + row*128;
    float dl = bf2f(dlH[row*DIN_+d]);
    float u  = bf2f(uH[row*DIN_+d]);
    float Bv[DSTATE_];
    const float4* pb = (const float4*)(rowp + 32);
    #pragma unroll
    for (int q=0;q<4;q++){
      float4 fb_ = pb[q]; Bv[4*q]=fb_.x; Bv[4*q+1]=fb_.y; Bv[4*q+2]=fb_.z; Bv[4*q+3]=fb_.w;
    }
    float du = dl*u;
    if (fast){
      float e1 = __expf(-dl);
      float p2 = e1*e1, p4 = p2*p2, p8 = p4*p4;
      float pw[DSTATE_];
      pw[0]=e1;      pw[1]=p2;       pw[2]=p2*e1;    pw[3]=p4;
      pw[4]=p4*e1;   pw[5]=p4*p2;    pw[6]=p4*pw[2]; pw[7]=p8;
      pw[8]=p8*e1;   pw[9]=p8*p2;    pw[10]=p8*pw[2];pw[11]=p8*p4;
      pw[12]=p8*pw[4];pw[13]=p8*pw[5];pw[14]=p8*pw[6];pw[15]=p8*p8;
      #pragma unroll
      for (int s=0;s<DSTATE_;s++) h[s] = pw[s]*h[s] + du*Bv[s];
    } else {
      #pragma unroll
      for (int s=0;s<DSTATE_;s++){ float a = __expf(dl*As[s]); h[s] = a*h[s] + du*Bv[s]; }
    }
    if (t >= t0){
      float Cv[DSTATE_];
      const float4* pc = (const float4*)(rowp + 48);
      #pragma unroll
      for (int q=0;q<4;q++){
        float4 fc_ = pc[q]; Cv[4*q]=fc_.x; Cv[4*q+1]=fc_.y; Cv[4*q+2]=fc_.z; Cv[4*q+3]=fc_.w;
      }
      float y = 0.f;
      #pragma unroll
      for (int s=0;s<DSTATE_;s++) y += h[s]*Cv[s];
      y += u*Dv;
      float z = bf2f(zH[row*DIN_+d]);
      float sil = z/(1.f+expf(-z));
      yH[row*DIN_+d] = f2bf(y*sil);
    }
  }
}

// ---------------- bf16 MFMA GEMM, 128x128 tile, BK=64, reg-staged padded LDS ----------------
enum { E_GELU_BF16=0, E_BF16=1, E_F32=2, E_MOE=3, E_SPLUS=4 };

template<int EPI>
__global__ __launch_bounds__(256,2)
void gemm_k(const unsigned short* __restrict__ A, int lda,
            const unsigned short* __restrict__ Bm, int ldb,
            int K,
            const float* __restrict__ bias,
            float* __restrict__ oF, unsigned short* __restrict__ oH, int ldo,
            const float* __restrict__ wfull, int ecol,
            const float* __restrict__ resid,
            unsigned short* __restrict__ oH2)
{
  __shared__ unsigned short As[128*72];
  __shared__ unsigned short Bs[128*72];
  int tid = threadIdx.x, lane = tid&63, wv = tid>>6;
  int wm = wv>>1, wn = wv&1;
  int nwg = gridDim.x*gridDim.y;
  int wg  = blockIdx.y*gridDim.x + blockIdx.x;
  int cpx = nwg >> 3;
  int swz = (wg & 7)*cpx + (wg >> 3);
  int bx = swz % gridDim.x, by = swz / gridDim.x;
  int mb = by*128, nb = bx*128;
  int g4 = (lane>>4)<<2;
  int r16 = lane & 15;
  f32x4 acc[4][4];
  #pragma unroll
  for (int i=0;i<4;i++)
    #pragma unroll
    for (int j=0;j<4;j++) acc[i][j] = (f32x4){0.f,0.f,0.f,0.f};

  for (int k0=0; k0<K; k0+=64) {
    #pragma unroll
    for (int i=0;i<4;i++){
      int c  = tid + (i<<8);
      int r  = c>>3, ko = (c&7)<<3;
      uint4 va = *(const uint4*)(A  + (size_t)(mb+r)*lda + k0+ko);
      uint4 vb = *(const uint4*)(Bm + (size_t)(nb+r)*ldb + k0+ko);
      *(uint4*)&As[r*72+ko] = va;
      *(uint4*)&Bs[r*72+ko] = vb;
    }
    __syncthreads();
    #pragma unroll
    for (int ks=0; ks<2; ks++){
      int kb = ks<<5;
      s16x8 fa[4], fb[4];
      #pragma unroll
      for (int mi=0;mi<4;mi++){
        const unsigned short* p = &As[(wm*64+mi*16+r16)*72 + kb + g4];
        union { uint64_t q[2]; s16x8 v; } u;
        u.q[0] = *(const uint64_t*)p;
        u.q[1] = *(const uint64_t*)(p+16);
        fa[mi] = u.v;
      }
      #pragma unroll
      for (int ni=0;ni<4;ni++){
        const unsigned short* p = &Bs[(wn*64+ni*16+r16)*72 + kb + g4];
        union { uint64_t q[2]; s16x8 v; } u;
        u.q[0] = *(const uint64_t*)p;
        u.q[1] = *(const uint64_t*)(p+16);
        fb[ni] = u.v;
      }
      #pragma unroll
      for (int mi=0;mi<4;mi++)
        #pragma unroll
        for (int ni=0;ni<4;ni++)
          acc[mi][ni] = __builtin_amdgcn_mfma_f32_16x16x32_bf16(fa[mi], fb[ni], acc[mi][ni], 0,0,0);
    }
    __syncthreads();
  }
  #pragma unroll
  for (int mi=0;mi<4;mi++){
    #pragma unroll
    for (int ni=0;ni<4;ni++){
      #pragma unroll
      for (int rr=0;rr<4;rr++){
        int row = mb + wm*64 + mi*16 + g4 + rr;
        int col = nb + wn*64 + ni*16 + r16;
        float v = acc[mi][ni][rr];
        if constexpr (EPI == E_GELU_BF16){
          v += bias[col];
          oH[(size_t)row*ldo + col] = f2bf(gelu_f(v));
        } else if constexpr (EPI == E_BF16){
          if (bias) v += bias[col];
          if (oH2 && col >= 1024) oH2[(size_t)row*1024 + col - 1024] = f2bf(v);
          else                    oH [(size_t)row*ldo  + col] = f2bf(v);
        } else if constexpr (EPI == E_F32){
          size_t o = (size_t)row*ldo + col;
          oF[o] = v;
          if (oH) oH[o] = f2bf(v);
        } else if constexpr (EPI == E_SPLUS){
          v += bias[col];
          v = (v > 20.f) ? v : log1pf(expf(v));
          oH[(size_t)row*ldo + col] = f2bf(v);
        } else { // E_MOE
          size_t o = (size_t)row*ldo + col;
          if (bias) v += bias[col];
          float w = wfull[(size_t)row*8 + ecol];
          float base = resid ? resid[o] : oF[o];
          oF[o] = base + w*v;
        }
      }
    }
  }
}

extern "C" void kernel_launch(void* const* d_in, const int* in_sizes, int n_in,
                              void* d_out, int out_size, void* d_ws, size_t ws_size,
                              hipStream_t stream)
{
  (void)in_sizes; (void)n_in; (void)out_size;
  const float* x      = (const float*)d_in[0];
  const float* ln_g   = (const float*)d_in[1];
  const float* ln_b   = (const float*)d_in[2];
  const float* gate_w = (const float*)d_in[3];
  const float* ent_w  = (const float*)d_in[4];
  const float* ent_b  = (const float*)d_in[5];
  const float* temp   = (const float*)d_in[6];
  const float* cin_w  = (const float*)d_in[7];
  const float* cin_b  = (const float*)d_in[8];
  const float* ck     = (const float*)d_in[9];
  const float* ck_b   = (const float*)d_in[10];
  const float* cout_w = (const float*)d_in[11];
  const float* cout_b = (const float*)d_in[12];
  const float* m_in   = (const float*)d_in[13];
  const float* m_cw   = (const float*)d_in[14];
  const float* m_cb   = (const float*)d_in[15];
  const float* m_xp   = (const float*)d_in[16];
  const float* m_dtw  = (const float*)d_in[17];
  const float* m_dtb  = (const float*)d_in[18];
  const float* m_alog = (const float*)d_in[19];
  const float* m_Dd   = (const float*)d_in[20];
  const float* m_op   = (const float*)d_in[21];
  float* out = (float*)d_out;
  char* ws = (char*)d_ws;

  size_t off = 0;
  auto alloc = [&](size_t bytes)->size_t{
    size_t r = off; off += (bytes + 4095) & ~(size_t)4095; return r;
  };
  size_t o_xnH  = alloc((size_t)BT_*DM*2);
  size_t o_wf   = alloc((size_t)BT_*8*4);
  size_t o_st   = alloc(4096);
  size_t o_wCI  = alloc((size_t)4*DIN_*DM*2);
  size_t o_wCO  = alloc((size_t)4*DM*DIN_*2);
  size_t o_wIP  = alloc((size_t)4*2048*DM*2);
  size_t o_wXP  = alloc((size_t)4*128*DIN_*2);
  size_t o_wOP  = alloc((size_t)4*DM*DIN_*2);
  size_t o_wDT  = alloc((size_t)4*DIN_*64*2);  // dt weights, K padded 32->64 (zeros)
  size_t o_A0   = alloc((size_t)BT_*DIN_*2);   // u_raw / conv H1 / y   | dftO (with A1)
  size_t o_A1   = alloc((size_t)BT_*DIN_*2);   // z                     | dftO tail
  size_t o_A3   = alloc((size_t)BT_*DIN_*2);   // u' / conv H2          | xnTH (bf16 T)
  size_t o_A4   = alloc((size_t)BT_*128*4);    // dbc f32               | dftW + rowent
  size_t o_A5   = alloc((size_t)BT_*128*2);    // dbc bf16 (for delta GEMM)
  size_t o_xnT  = alloc((size_t)BT_*DM*4);     // f32 xn transposed     | delta bf16 (scan)
  size_t need = off;

  if (ws_size < need){
    diag_k<<<1,1,0,stream>>>(out, (float)(ws_size >> 20));
    return;
  }

  unsigned short* xnH  = (unsigned short*)(ws + o_xnH);
  float*          xnT  = (float*)(ws + o_xnT);
  float*          wfull= (float*)(ws + o_wf);
  float*          entP = (float*)(ws + o_st);
  float*          gtpe = (float*)(ws + o_st + 512);
  float*          gavg = (float*)(ws + o_st + 544);
  unsigned short* wtCI = (unsigned short*)(ws + o_wCI);
  unsigned short* wtCO = (unsigned short*)(ws + o_wCO);
  unsigned short* wtIP = (unsigned short*)(ws + o_wIP);
  unsigned short* wtXP = (unsigned short*)(ws + o_wXP);
  unsigned short* wtOP = (unsigned short*)(ws + o_wOP);
  unsigned short* wtDT = (unsigned short*)(ws + o_wDT);
  unsigned short* a0H  = (unsigned short*)(ws + o_A0);
  unsigned short* a1H  = (unsigned short*)(ws + o_A1);
  unsigned short* a3H  = (unsigned short*)(ws + o_A3);
  float*          a4F  = (float*)(ws + o_A4);
  unsigned short* a5H  = (unsigned short*)(ws + o_A5);
  // entropy-phase aliases (used only before experts run)
  float*          dftO   = (float*)(ws + o_A0);              // 65 MB < A0+A1
  unsigned short* xnTH   = (unsigned short*)(ws + o_A3);     // 16.8 MB < 33.5 MB
  unsigned short* dftW   = (unsigned short*)(ws + o_A4);     // 128 KB
  float*          rowent = (float*)(ws + o_A4 + (512<<10));  // 254 KB
  // expert-phase alias: delta bf16 lives in the dead xnT region
  unsigned short* dlH    = (unsigned short*)(ws + o_xnT);    // 33.5 MB < 67 MB

  hipMemsetAsync(ws + o_st, 0, 4096, stream);
  hipMemsetAsync(ws + o_wDT, 0, (size_t)4*DIN_*64*2, stream);

  transpose_cvt<<<dim3(32,16,4),256,0,stream>>>(cin_w,  wtCI, 512, 1024, 1024, 512);
  transpose_cvt<<<dim3(16,32,4),256,0,stream>>>(cout_w, wtCO, 1024, 512, 512, 1024);
  transpose_cvt<<<dim3(64,16,4),256,0,stream>>>(m_in,   wtIP, 512, 2048, 2048, 512);
  transpose_cvt<<<dim3( 4,32,4),256,0,stream>>>(m_xp,   wtXP, 1024, 64, 128, 1024);
  transpose_cvt<<<dim3(16,32,4),256,0,stream>>>(m_op,   wtOP, 1024, 512, 512, 1024);
  transpose_cvt<<<dim3(32, 1,4),256,0,stream>>>(m_dtw,  wtDT, 32, 1024, 1024, 64);
  dft_init<<<256,256,0,stream>>>(dftW);

  ln_kernel<<<BT_/64,256,0,stream>>>(x, ln_g, ln_b, xnT, xnTH, xnH);
  dft_gemm<<<dim3(2, NWIN*4),256,0,stream>>>(xnTH, dftW, dftO);
  ent_reduce<<<NWIN*512/4,256,0,stream>>>(dftO, xnTH, rowent);
  ent_stage2<<<NWIN,256,0,stream>>>(rowent, entP);
  gating_kernel<<<BT_/64,256,0,stream>>>(xnT, gate_w, ent_w, ent_b, temp, entP, wfull, gtpe, gavg);

  // conv experts (0..3)
  for (int e=0;e<4;e++){
    gemm_k<E_GELU_BF16><<<dim3(8,128),256,0,stream>>>(
        xnH, DM, wtCI + (size_t)e*DIN_*DM, DM, DM,
        cin_b + (size_t)e*DIN_, nullptr, a0H, DIN_, nullptr, 0, nullptr, nullptr);
    dwconv7_gelu<<<BT_*DIN_/8/256,256,0,stream>>>(a0H, ck + (size_t)e*DIN_*7, ck_b + (size_t)e*DIN_, a3H);
    gemm_k<E_MOE><<<dim3(4,128),256,0,stream>>>(
        a3H, DIN_, wtCO + (size_t)e*DM*DIN_, DIN_, DIN_,
        cout_b + (size_t)e*DM, out, nullptr, DM, wfull, e, (e==0)? x : nullptr, nullptr);
  }

  // mamba experts (4..7)
  for (int e=0;e<4;e++){
    gemm_k<E_BF16><<<dim3(16,128),256,0,stream>>>(
        xnH, DM, wtIP + (size_t)e*2048*DM, DM, DM,
        nullptr, nullptr, a0H, DIN_, nullptr, 0, nullptr, a1H);            // u_raw + z split
    dwconv4_silu<<<BT_*DIN_/8/256,256,0,stream>>>(a0H, m_cw + (size_t)e*DIN_*4, m_cb + (size_t)e*DIN_, a3H);
    gemm_k<E_F32><<<dim3(1,128),256,0,stream>>>(
        a3H, DIN_, wtXP + (size_t)e*128*DIN_, DIN_, DIN_,
        nullptr, a4F, a5H, 128, nullptr, 0, nullptr, nullptr);             // dbc (f32 + bf16)
    gemm_k<E_SPLUS><<<dim3(8,128),256,0,stream>>>(
        a5H, 128, wtDT + (size_t)e*DIN_*64, 64, 64,
        m_dtb + (size_t)e*DIN_, nullptr, dlH, DIN_, nullptr, 0, nullptr, nullptr); // delta
    scan_k<<<1024,256,0,stream>>>(a4F, dlH, a3H, a1H,
        m_alog + (size_t)e*DIN_*DSTATE_, m_Dd + (size_t)e*DIN_, a0H);      // y -> a0H
    gemm_k<E_MOE><<<dim3(4,128),256,0,stream>>>(
        a0H, DIN_, wtOP + (size_t)e*DM*DIN_, DIN_, DIN_,
        nullptr, out, nullptr, DM, wfull, 4+e, nullptr, nullptr);
  }

  aux_kernel<<<1,1,0,stream>>>(gtpe, gavg, out);
}

// Round 10
// 2067.260 us; speedup vs baseline: 1.9559x; 1.5145x over previous
//
#include <hip/hip_runtime.h>
#include <stdint.h>

// ---------------- problem constants ----------------
#define Bb    4
#define Tt    4096
#define DM    512
#define DIN_  1024
#define BT_   16384        // Bb*Tt
#define NW    31           // entropy windows: (4096-256)/128+1
#define DSTATE_ 16
#define NWIN  124          // Bb*NW

typedef float f32x4 __attribute__((ext_vector_type(4)));
typedef short s16x8 __attribute__((ext_vector_type(8)));

static __device__ __forceinline__ float bf2f(unsigned short h){
  union { unsigned int u; float f; } v; v.u = ((unsigned int)h)<<16; return v.f;
}
static __device__ __forceinline__ unsigned short f2bf(float f){
  union { float f; unsigned int u; } v; v.f = f;
  unsigned int u = v.u + 0x7fffu + ((v.u>>16)&1u);   // RTNE
  return (unsigned short)(u>>16);
}
static __device__ __forceinline__ float gelu_f(float x){
  return 0.5f*x*(1.0f+erff(x*0.7071067811865476f));
}

__global__ void diag_k(float* out, float v){ out[0] = v; }

// ---------------- LayerNorm: 64-token tiles -> xnT (f32 T) + xnTH (bf16 T) + xnH (bf16 row) ----------------
__global__ __launch_bounds__(256)
void ln_kernel(const float* __restrict__ x, const float* __restrict__ g,
               const float* __restrict__ be, float* __restrict__ xnT,
               unsigned short* __restrict__ xnTH, unsigned short* __restrict__ xnH)
{
  __shared__ float mrs[64][2];
  __shared__ __align__(16) float tile[64][33];
  int tid = threadIdx.x, lane = tid&63, wv = tid>>6;
  int r0 = blockIdx.x*64;
  for (int j=0;j<16;j++){
    int r = r0 + wv*16 + j;
    const float4* px = (const float4*)(x + (size_t)r*DM);
    float4 a = px[lane*2], b4 = px[lane*2+1];
    float s1 = a.x+a.y+a.z+a.w + b4.x+b4.y+b4.z+b4.w;
    float s2 = a.x*a.x+a.y*a.y+a.z*a.z+a.w*a.w + b4.x*b4.x+b4.y*b4.y+b4.z*b4.z+b4.w*b4.w;
    #pragma unroll
    for (int o=32;o>=1;o>>=1){ s1 += __shfl_xor(s1,o); s2 += __shfl_xor(s2,o); }
    if (lane==0){
      float m = s1*(1.f/DM);
      float var = s2*(1.f/DM) - m*m;
      mrs[wv*16+j][0] = m;
      mrs[wv*16+j][1] = rsqrtf(var + 1e-5f);
    }
  }
  __syncthreads();
  for (int d0=0; d0<DM; d0+=32){
    #pragma unroll
    for (int q=0;q<8;q++){
      int tk = q*8 + (tid>>5);
      int dj = tid & 31;
      int r = r0+tk, d = d0+dj;
      float v = x[(size_t)r*DM + d];
      float nv = (v - mrs[tk][0])*mrs[tk][1]*g[d] + be[d];
      tile[tk][dj] = nv;
      xnH[(size_t)r*DM + d] = f2bf(nv);
    }
    __syncthreads();
    #pragma unroll
    for (int q=0;q<8;q++){
      int dj = q*4 + (tid>>6);
      int tk = tid & 63;
      float v = tile[tk][dj];
      xnT [(size_t)(d0+dj)*BT_ + r0 + tk] = v;
      xnTH[(size_t)(d0+dj)*BT_ + r0 + tk] = f2bf(v);
    }
    __syncthreads();
  }
}

// ---------------- weight transpose + f32->bf16: (E,K,N) -> (E,Npad,K-stride Kpad) ----------------
__global__ __launch_bounds__(256)
void transpose_cvt(const float* __restrict__ src, unsigned short* __restrict__ dst,
                   int K, int N, int Npad, int Kpad)
{
  __shared__ float tile[32][33];
  int e = blockIdx.z;
  int n0 = blockIdx.x<<5, k0 = blockIdx.y<<5;
  int tx = threadIdx.x & 31, ty = threadIdx.x >> 5;
  #pragma unroll
  for (int i=0;i<4;i++){
    int k = k0 + ty + i*8, n = n0 + tx;
    float v = (n < N) ? src[((size_t)e*K + k)*N + n] : 0.f;
    tile[ty+i*8][tx] = v;
  }
  __syncthreads();
  #pragma unroll
  for (int i=0;i<4;i++){
    int n = n0 + ty + i*8, k = k0 + tx;
    if (n < Npad) dst[((size_t)e*Npad + n)*Kpad + k] = f2bf(tile[tx][ty+i*8]);
  }
}

// ---------------- conv weight transpose: (E,D,K) -> (E,K,D) f32 ----------------
__global__ __launch_bounds__(256)
void convw_prep(const float* __restrict__ src, float* __restrict__ dst, int D, int K)
{
  int e = blockIdx.x / K, j = blockIdx.x % K;
  for (int d = threadIdx.x; d < D; d += 256)
    dst[((size_t)e*K + j)*D + d] = src[((size_t)e*D + d)*K + j];
}

// ---------------- DFT weight matrix ----------------
__global__ void dft_init(unsigned short* __restrict__ w)
{
  int n = blockIdx.x, k = threadIdx.x;
  int bin = (n < 128) ? n+1 : n-127;
  int idx = (bin*k) & 255;                    // exact integer angle reduction
  float ang = 6.283185307179586f * (float)idx / 256.f;
  float sv, cv; sincosf(ang, &sv, &cv);
  w[n*256 + k] = f2bf((n < 128) ? cv : sv);
}

// ---------------- DFT GEMM: per (window, d-block) 128x128x256 bf16 MFMA ----------------
__global__ __launch_bounds__(256,2)
void dft_gemm(const unsigned short* __restrict__ xnTH, const unsigned short* __restrict__ dftW,
              float* __restrict__ dftO)
{
  __shared__ unsigned short As[128*72];
  __shared__ unsigned short Bs[128*72];
  int tid = threadIdx.x, lane = tid&63, wv = tid>>6;
  int wm = wv>>1, wn = wv&1;
  int win = blockIdx.y >> 2, dblk = blockIdx.y & 3;
  int woff = (win/NW)*Tt + (win%NW)*128;
  int mb = dblk*128;
  int nb = blockIdx.x*128;
  int g4 = (lane>>4)<<2;
  int r16 = lane & 15;
  f32x4 acc[4][4];
  #pragma unroll
  for (int i=0;i<4;i++)
    #pragma unroll
    for (int j=0;j<4;j++) acc[i][j] = (f32x4){0.f,0.f,0.f,0.f};

  for (int k0=0; k0<256; k0+=64) {
    #pragma unroll
    for (int i=0;i<4;i++){
      int c  = tid + (i<<8);
      int r  = c>>3, ko = (c&7)<<3;
      uint4 va = *(const uint4*)(xnTH + (size_t)(mb+r)*BT_ + woff + k0+ko);
      uint4 vb = *(const uint4*)(dftW + (size_t)(nb+r)*256 + k0+ko);
      *(uint4*)&As[r*72+ko] = va;
      *(uint4*)&Bs[r*72+ko] = vb;
    }
    __syncthreads();
    #pragma unroll
    for (int ks=0; ks<2; ks++){
      int kb = ks<<5;
      s16x8 fa[4], fb[4];
      #pragma unroll
      for (int mi=0;mi<4;mi++){
        const unsigned short* p = &As[(wm*64+mi*16+r16)*72 + kb + g4];
        union { uint64_t q[2]; s16x8 v; } u;
        u.q[0] = *(const uint64_t*)p;
        u.q[1] = *(const uint64_t*)(p+16);
        fa[mi] = u.v;
      }
      #pragma unroll
      for (int ni=0;ni<4;ni++){
        const unsigned short* p = &Bs[(wn*64+ni*16+r16)*72 + kb + g4];
        union { uint64_t q[2]; s16x8 v; } u;
        u.q[0] = *(const uint64_t*)p;
        u.q[1] = *(const uint64_t*)(p+16);
        fb[ni] = u.v;
      }
      #pragma unroll
      for (int mi=0;mi<4;mi++)
        #pragma unroll
        for (int ni=0;ni<4;ni++)
          acc[mi][ni] = __builtin_amdgcn_mfma_f32_16x16x32_bf16(fa[mi], fb[ni], acc[mi][ni], 0,0,0);
    }
    __syncthreads();
  }
  #pragma unroll
  for (int mi=0;mi<4;mi++){
    #pragma unroll
    for (int ni=0;ni<4;ni++){
      #pragma unroll
      for (int rr=0;rr<4;rr++){
        int row = win*512 + mb + wm*64 + mi*16 + g4 + rr;
        int col = nb + wn*64 + ni*16 + r16;
        dftO[(size_t)row*256 + col] = acc[mi][ni][rr];
      }
    }
  }
}

// ---------------- entropy reduce stage 1: one wave per (window,d) row, NO atomics ----------------
__global__ __launch_bounds__(256)
void ent_reduce(const float* __restrict__ dftO, const unsigned short* __restrict__ xnTH,
                float* __restrict__ rowent)
{
  int tid = threadIdx.x, lane = tid&63, wv = tid>>6;
  int row = blockIdx.x*4 + wv;            // 0..63487
  int win = row >> 9, d = row & 511;
  int b = win / NW, w = win - b*NW;
  size_t sb = (size_t)d*BT_ + (size_t)b*Tt + (size_t)w*128;
  union { uint64_t q; unsigned short s[4]; } u;
  u.q = *(const uint64_t*)(xnTH + sb + lane*4);
  float lsum = bf2f(u.s[0])+bf2f(u.s[1])+bf2f(u.s[2])+bf2f(u.s[3]);
  #pragma unroll
  for (int o=32;o>=1;o>>=1) lsum += __shfl_xor(lsum,o);
  const float* r = dftO + (size_t)row*256;
  float c1 = r[lane], c2 = r[64+lane], s1 = r[128+lane], s2 = r[192+lane];
  float m1 = sqrtf(c1*c1+s1*s1) + 1e-10f;
  float m2 = sqrtf(c2*c2+s2*s2) + 1e-10f;
  float m0 = fabsf(lsum) + 1e-10f;
  float ps = m1 + m2 + ((lane==0)? m0 : 0.f);
  #pragma unroll
  for (int o=32;o>=1;o>>=1) ps += __shfl_xor(ps,o);
  float inv = 1.f/ps;
  float p1 = m1*inv, p2 = m2*inv;
  float es = -p1*logf(p1+1e-10f) - p2*logf(p2+1e-10f);
  if (lane==0){ float p0 = m0*inv; es -= p0*logf(p0+1e-10f); }
  #pragma unroll
  for (int o=32;o>=1;o>>=1) es += __shfl_xor(es,o);
  if (lane==0) rowent[row] = es*(1.f/4.859812404361672f);   // /ln(129)
}

// ---------------- entropy reduce stage 2 ----------------
__global__ __launch_bounds__(256)
void ent_stage2(const float* __restrict__ rowent, float* __restrict__ entP)
{
  __shared__ float r4[4];
  int win = blockIdx.x, tid = threadIdx.x, lane = tid&63, wv = tid>>6;
  const float* p = rowent + (size_t)win*512;
  float s = p[tid] + p[tid+256];
  #pragma unroll
  for (int o=32;o>=1;o>>=1) s += __shfl_xor(s,o);
  if (lane==0) r4[wv] = s;
  __syncthreads();
  if (tid==0) entP[win] = r4[0]+r4[1]+r4[2]+r4[3];
}

// ---------------- gating: 64-token tiles, coalesced xnT reads ----------------
__global__ __launch_bounds__(256)
void gating_kernel(const float* __restrict__ xnT, const float* __restrict__ gw,
                   const float* __restrict__ entw, const float* __restrict__ entb,
                   const float* __restrict__ temp, const float* __restrict__ ent_partial,
                   float* __restrict__ wfull, float* __restrict__ g_tpe, float* __restrict__ g_avg)
{
  __shared__ __align__(16) float accs[4][64][8];
  __shared__ float l_tpe[8], l_avg[8];
  int tid = threadIdx.x, lane = tid&63, wv = tid>>6;
  int r0 = blockIdx.x*64;
  if (tid < 8){ l_tpe[tid]=0.f; l_avg[tid]=0.f; }
  float acc[8];
  #pragma unroll
  for (int e=0;e<8;e++) acc[e]=0.f;
  for (int i=0;i<128;i++){
    int dd = wv*128 + i;
    float xv = xnT[(size_t)dd*BT_ + r0 + lane];
    const float4* g4p = (const float4*)(gw + (size_t)dd*8);
    float4 w0 = g4p[0], w1 = g4p[1];
    acc[0]+=xv*w0.x; acc[1]+=xv*w0.y; acc[2]+=xv*w0.z; acc[3]+=xv*w0.w;
    acc[4]+=xv*w1.x; acc[5]+=xv*w1.y; acc[6]+=xv*w1.z; acc[7]+=xv*w1.w;
  }
  #pragma unroll
  for (int e=0;e<8;e++) accs[wv][lane][e] = acc[e];
  __syncthreads();
  if (wv==0){
    int r = r0 + lane;
    int b = r0 >> 12;
    float ep = 0.f;
    for (int i=0;i<NW;i++) ep += ent_partial[b*NW+i];
    float ent = ep * (1.f/(NW*512.f));
    float lg[8];
    #pragma unroll
    for (int e=0;e<8;e++)
      lg[e] = accs[0][lane][e]+accs[1][lane][e]+accs[2][lane][e]+accs[3][lane][e];
    float invT = 1.f/(fabsf(temp[0])+1e-6f);
    #pragma unroll
    for (int e=0;e<8;e++) lg[e] = (lg[e] + ent*entw[e] + entb[e]) * invT;
    int i0=0; float v0=lg[0];
    #pragma unroll
    for (int e=1;e<8;e++) if (lg[e] > v0){ v0=lg[e]; i0=e; }
    int i1=-1; float v1=-1e30f;
    #pragma unroll
    for (int e=0;e<8;e++) if (e!=i0 && lg[e] > v1){ v1=lg[e]; i1=e; }
    float e1 = expf(v1-v0);
    float rw0 = 1.f/(1.f+e1), rw1 = e1/(1.f+e1);
    float pr[8], se=0.f;
    #pragma unroll
    for (int e=0;e<8;e++){ pr[e]=expf(lg[e]-v0); se+=pr[e]; }
    float ise = 1.f/se;
    #pragma unroll
    for (int e=0;e<8;e++) wfull[(size_t)r*8+e] = (e==i0)?rw0 : ((e==i1)?rw1 : 0.f);
    atomicAdd(&l_tpe[i0],1.f); atomicAdd(&l_tpe[i1],1.f);
    #pragma unroll
    for (int e=0;e<8;e++) atomicAdd(&l_avg[e], pr[e]*ise);
  }
  __syncthreads();
  if (tid < 8){ atomicAdd(&g_tpe[tid], l_tpe[tid]); atomicAdd(&g_avg[tid], l_avg[tid]); }
}

__global__ void aux_kernel(const float* __restrict__ g_tpe, const float* __restrict__ g_avg,
                           float* __restrict__ out)
{
  float a=0.f;
  #pragma unroll
  for (int e=0;e<8;e++) a += (g_tpe[e]*(1.f/BT_)) * (g_avg[e]*(1.f/BT_));
  out[(size_t)BT_*DM] = 8.f*a;
}

// ---------------- depthwise causal convs (8 ch/thread, transposed [taps][DIN] weights) ----------------
__global__ __launch_bounds__(256)
void dwconv7_gelu(const unsigned short* __restrict__ H1, const float* __restrict__ k7T,
                  const float* __restrict__ kb, unsigned short* __restrict__ H2)
{
  size_t gid = (size_t)blockIdx.x*256 + threadIdx.x;
  int dg = (int)(gid & 127);
  size_t row = gid >> 7;
  int t = (int)(row & (Tt-1));
  int d0 = dg*8;
  float4 b0 = *(const float4*)&kb[d0];
  float4 b1 = *(const float4*)&kb[d0+4];
  float acc[8] = {b0.x,b0.y,b0.z,b0.w, b1.x,b1.y,b1.z,b1.w};
  #pragma unroll
  for (int j=0;j<7;j++){
    int off = 6-j;
    if (t - off >= 0){
      float4 w0 = *(const float4*)&k7T[j*DIN_ + d0];
      float4 w1 = *(const float4*)&k7T[j*DIN_ + d0 + 4];
      float wv[8] = {w0.x,w0.y,w0.z,w0.w, w1.x,w1.y,w1.z,w1.w};
      union { uint4 v; unsigned short s[8]; } u;
      u.v = *(const uint4*)(H1 + (row-(size_t)off)*DIN_ + d0);
      #pragma unroll
      for (int i=0;i<8;i++) acc[i] += bf2f(u.s[i]) * wv[i];
    }
  }
  union { uint4 v; unsigned short s[8]; } o;
  #pragma unroll
  for (int i=0;i<8;i++) o.s[i] = f2bf(gelu_f(acc[i]));
  *(uint4*)(H2 + row*DIN_ + d0) = o.v;
}

__global__ __launch_bounds__(256)
void dwconv4_silu(const unsigned short* __restrict__ U, const float* __restrict__ cwT,
                  const float* __restrict__ cb, unsigned short* __restrict__ uH)
{
  size_t gid = (size_t)blockIdx.x*256 + threadIdx.x;
  int dg = (int)(gid & 127);
  size_t row = gid >> 7;
  int t = (int)(row & (Tt-1));
  int d0 = dg*8;
  float4 b0 = *(const float4*)&cb[d0];
  float4 b1 = *(const float4*)&cb[d0+4];
  float acc[8] = {b0.x,b0.y,b0.z,b0.w, b1.x,b1.y,b1.z,b1.w};
  #pragma unroll
  for (int j=0;j<4;j++){
    int off = 3-j;
    if (t - off >= 0){
      float4 w0 = *(const float4*)&cwT[j*DIN_ + d0];
      float4 w1 = *(const float4*)&cwT[j*DIN_ + d0 + 4];
      float wv[8] = {w0.x,w0.y,w0.z,w0.w, w1.x,w1.y,w1.z,w1.w};
      union { uint4 v; unsigned short s[8]; } u;
      u.v = *(const uint4*)(U + (row-(size_t)off)*DIN_ + d0);
      #pragma unroll
      for (int i=0;i<8;i++) acc[i] += bf2f(u.s[i]) * wv[i];
    }
  }
  union { uint4 v; unsigned short s[8]; } o;
  #pragma unroll
  for (int i=0;i<8;i++){ float v = acc[i]; o.s[i] = f2bf(v/(1.f+expf(-v))); }
  *(uint4*)(uH + row*DIN_ + d0) = o.v;
}

// ---------------- chunk-parallel selective scan: precomputed delta, 64-step chunks ----------------
__global__ __launch_bounds__(256)
void scan_k(const float* __restrict__ dbc, const unsigned short* __restrict__ dlH,
            const unsigned short* __restrict__ uH, const unsigned short* __restrict__ zH,
            const float* __restrict__ Alog, const float* __restrict__ Dp,
            unsigned short* __restrict__ yH)
{
  int tid = threadIdx.x;
  int blk = blockIdx.x;
  int dblk = blk & 3, chunk = (blk>>2) & 63, b = blk>>8;
  int d = dblk*256 + tid;
  int t0 = chunk*64, t1 = t0+64;
  int t = (t0 >= 64) ? t0-64 : 0;     // warmup: decay <= e^-38 typ, negligible
  float As[DSTATE_];
  bool fastb = true;
  #pragma unroll
  for (int s=0;s<DSTATE_;s++){
    As[s] = -expf(Alog[(size_t)d*DSTATE_+s]);
    if (fabsf(As[s] + (float)(s+1)) > 1e-3f) fastb=false;
  }
  int fast = __all((int)fastb);
  float Dv = Dp[d];
  float h[DSTATE_];
  #pragma unroll
  for (int s=0;s<DSTATE_;s++) h[s]=0.f;
  for (; t<t1; ++t){
    size_t row = ((size_t)b<<12) + t;
    const float* rowp = dbc + row*128;
    float dl = bf2f(dlH[row*DIN_+d]);
    float u  = bf2f(uH[row*DIN_+d]);
    float Bv[DSTATE_];
    const float4* pb = (const float4*)(rowp + 32);
    #pragma unroll
    for (int q=0;q<4;q++){
      float4 fb_ = pb[q]; Bv[4*q]=fb_.x; Bv[4*q+1]=fb_.y; Bv[4*q+2]=fb_.z; Bv[4*q+3]=fb_.w;
    }
    float du = dl*u;
    if (fast){
      float e1 = __expf(-dl);
      float p2 = e1*e1, p4 = p2*p2, p8 = p4*p4;
      float pw[DSTATE_];
      pw[0]=e1;      pw[1]=p2;       pw[2]=p2*e1;    pw[3]=p4;
      pw[4]=p4*e1;   pw[5]=p4*p2;    pw[6]=p4*pw[2]; pw[7]=p8;
      pw[8]=p8*e1;   pw[9]=p8*p2;    pw[10]=p8*pw[2];pw[11]=p8*p4;
      pw[12]=p8*pw[4];pw[13]=p8*pw[5];pw[14]=p8*pw[6];pw[15]=p8*p8;
      #pragma unroll
      for (int s=0;s<DSTATE_;s++) h[s] = pw[s]*h[s] + du*Bv[s];
    } else {
      #pragma unroll
      for (int s=0;s<DSTATE_;s++){ float a = __expf(dl*As[s]); h[s] = a*h[s] + du*Bv[s]; }
    }
    if (t >= t0){
      float Cv[DSTATE_];
      const float4* pc = (const float4*)(rowp + 48);
      #pragma unroll
      for (int q=0;q<4;q++){
        float4 fc_ = pc[q]; Cv[4*q]=fc_.x; Cv[4*q+1]=fc_.y; Cv[4*q+2]=fc_.z; Cv[4*q+3]=fc_.w;
      }
      float y = 0.f;
      #pragma unroll
      for (int s=0;s<DSTATE_;s++) y += h[s]*Cv[s];
      y += u*Dv;
      float z = bf2f(zH[row*DIN_+d]);
      float sil = z/(1.f+expf(-z));
      yH[row*DIN_+d] = f2bf(y*sil);
    }
  }
}

// ---------------- bf16 MFMA GEMM, 128x128 tile, BK=64, reg-staged padded LDS ----------------
enum { E_GELU_BF16=0, E_BF16=1, E_F32=2, E_MOE=3, E_SPLUS=4 };

template<int EPI>
__global__ __launch_bounds__(256,2)
void gemm_k(const unsigned short* __restrict__ A, int lda,
            const unsigned short* __restrict__ Bm, int ldb,
            int K,
            const float* __restrict__ bias,
            float* __restrict__ oF, unsigned short* __restrict__ oH, int ldo,
            const float* __restrict__ wfull, int ecol,
            const float* __restrict__ resid,
            unsigned short* __restrict__ oH2)
{
  __shared__ unsigned short As[128*72];
  __shared__ unsigned short Bs[128*72];
  int tid = threadIdx.x, lane = tid&63, wv = tid>>6;
  int wm = wv>>1, wn = wv&1;
  int nwg = gridDim.x*gridDim.y;
  int wg  = blockIdx.y*gridDim.x + blockIdx.x;
  int cpx = nwg >> 3;
  int swz = (wg & 7)*cpx + (wg >> 3);
  int bx = swz % gridDim.x, by = swz / gridDim.x;
  int mb = by*128, nb = bx*128;
  int g4 = (lane>>4)<<2;
  int r16 = lane & 15;
  f32x4 acc[4][4];
  #pragma unroll
  for (int i=0;i<4;i++)
    #pragma unroll
    for (int j=0;j<4;j++) acc[i][j] = (f32x4){0.f,0.f,0.f,0.f};

  for (int k0=0; k0<K; k0+=64) {
    #pragma unroll
    for (int i=0;i<4;i++){
      int c  = tid + (i<<8);
      int r  = c>>3, ko = (c&7)<<3;
      uint4 va = *(const uint4*)(A  + (size_t)(mb+r)*lda + k0+ko);
      uint4 vb = *(const uint4*)(Bm + (size_t)(nb+r)*ldb + k0+ko);
      *(uint4*)&As[r*72+ko] = va;
      *(uint4*)&Bs[r*72+ko] = vb;
    }
    __syncthreads();
    #pragma unroll
    for (int ks=0; ks<2; ks++){
      int kb = ks<<5;
      s16x8 fa[4], fb[4];
      #pragma unroll
      for (int mi=0;mi<4;mi++){
        const unsigned short* p = &As[(wm*64+mi*16+r16)*72 + kb + g4];
        union { uint64_t q[2]; s16x8 v; } u;
        u.q[0] = *(const uint64_t*)p;
        u.q[1] = *(const uint64_t*)(p+16);
        fa[mi] = u.v;
      }
      #pragma unroll
      for (int ni=0;ni<4;ni++){
        const unsigned short* p = &Bs[(wn*64+ni*16+r16)*72 + kb + g4];
        union { uint64_t q[2]; s16x8 v; } u;
        u.q[0] = *(const uint64_t*)p;
        u.q[1] = *(const uint64_t*)(p+16);
        fb[ni] = u.v;
      }
      #pragma unroll
      for (int mi=0;mi<4;mi++)
        #pragma unroll
        for (int ni=0;ni<4;ni++)
          acc[mi][ni] = __builtin_amdgcn_mfma_f32_16x16x32_bf16(fa[mi], fb[ni], acc[mi][ni], 0,0,0);
    }
    __syncthreads();
  }
  #pragma unroll
  for (int mi=0;mi<4;mi++){
    #pragma unroll
    for (int ni=0;ni<4;ni++){
      #pragma unroll
      for (int rr=0;rr<4;rr++){
        int row = mb + wm*64 + mi*16 + g4 + rr;
        int col = nb + wn*64 + ni*16 + r16;
        float v = acc[mi][ni][rr];
        if constexpr (EPI == E_GELU_BF16){
          v += bias[col];
          oH[(size_t)row*ldo + col] = f2bf(gelu_f(v));
        } else if constexpr (EPI == E_BF16){
          if (bias) v += bias[col];
          if (oH2 && col >= 1024) oH2[(size_t)row*1024 + col - 1024] = f2bf(v);
          else                    oH [(size_t)row*ldo  + col] = f2bf(v);
        } else if constexpr (EPI == E_F32){
          size_t o = (size_t)row*ldo + col;
          oF[o] = v;
          if (oH) oH[o] = f2bf(v);
        } else if constexpr (EPI == E_SPLUS){
          v += bias[col];
          v = (v > 20.f) ? v : log1pf(expf(v));
          oH[(size_t)row*ldo + col] = f2bf(v);
        } else { // E_MOE
          size_t o = (size_t)row*ldo + col;
          if (bias) v += bias[col];
          float w = wfull[(size_t)row*8 + ecol];
          float base = resid ? resid[o] : oF[o];
          oF[o] = base + w*v;
        }
      }
    }
  }
}

extern "C" void kernel_launch(void* const* d_in, const int* in_sizes, int n_in,
                              void* d_out, int out_size, void* d_ws, size_t ws_size,
                              hipStream_t stream)
{
  (void)in_sizes; (void)n_in; (void)out_size;
  const float* x      = (const float*)d_in[0];
  const float* ln_g   = (const float*)d_in[1];
  const float* ln_b   = (const float*)d_in[2];
  const float* gate_w = (const float*)d_in[3];
  const float* ent_w  = (const float*)d_in[4];
  const float* ent_b  = (const float*)d_in[5];
  const float* temp   = (const float*)d_in[6];
  const float* cin_w  = (const float*)d_in[7];
  const float* cin_b  = (const float*)d_in[8];
  const float* ck     = (const float*)d_in[9];
  const float* ck_b   = (const float*)d_in[10];
  const float* cout_w = (const float*)d_in[11];
  const float* cout_b = (const float*)d_in[12];
  const float* m_in   = (const float*)d_in[13];
  const float* m_cw   = (const float*)d_in[14];
  const float* m_cb   = (const float*)d_in[15];
  const float* m_xp   = (const float*)d_in[16];
  const float* m_dtw  = (const float*)d_in[17];
  const float* m_dtb  = (const float*)d_in[18];
  const float* m_alog = (const float*)d_in[19];
  const float* m_Dd   = (const float*)d_in[20];
  const float* m_op   = (const float*)d_in[21];
  float* out = (float*)d_out;
  char* ws = (char*)d_ws;

  size_t off = 0;
  auto alloc = [&](size_t bytes)->size_t{
    size_t r = off; off += (bytes + 4095) & ~(size_t)4095; return r;
  };
  size_t o_xnH  = alloc((size_t)BT_*DM*2);
  size_t o_wf   = alloc((size_t)BT_*8*4);
  size_t o_st   = alloc(4096);
  size_t o_wCI  = alloc((size_t)4*DIN_*DM*2);
  size_t o_wCO  = alloc((size_t)4*DM*DIN_*2);
  size_t o_wIP  = alloc((size_t)4*2048*DM*2);
  size_t o_wXP  = alloc((size_t)4*128*DIN_*2);
  size_t o_wOP  = alloc((size_t)4*DM*DIN_*2);
  size_t o_wDT  = alloc((size_t)4*DIN_*64*2);  // dt weights, K padded 32->64 (zeros)
  size_t o_wK7  = alloc((size_t)4*7*DIN_*4);   // conv k transposed [e][7][1024] f32
  size_t o_wC4  = alloc((size_t)4*4*DIN_*4);   // mamba conv w transposed [e][4][1024] f32
  size_t o_A0   = alloc((size_t)BT_*DIN_*2);   // u_raw / conv H1 / y   | dftO (with A1)
  size_t o_A1   = alloc((size_t)BT_*DIN_*2);   // z                     | dftO tail
  size_t o_A3   = alloc((size_t)BT_*DIN_*2);   // u' / conv H2          | xnTH (bf16 T)
  size_t o_A4   = alloc((size_t)BT_*128*4);    // dbc f32               | dftW + rowent
  size_t o_A5   = alloc((size_t)BT_*128*2);    // dbc bf16 (for delta GEMM)
  size_t o_xnT  = alloc((size_t)BT_*DM*4);     // f32 xn transposed     | delta bf16 (scan)
  size_t need = off;

  if (ws_size < need){
    diag_k<<<1,1,0,stream>>>(out, (float)(ws_size >> 20));
    return;
  }

  unsigned short* xnH  = (unsigned short*)(ws + o_xnH);
  float*          xnT  = (float*)(ws + o_xnT);
  float*          wfull= (float*)(ws + o_wf);
  float*          entP = (float*)(ws + o_st);
  float*          gtpe = (float*)(ws + o_st + 512);
  float*          gavg = (float*)(ws + o_st + 544);
  unsigned short* wtCI = (unsigned short*)(ws + o_wCI);
  unsigned short* wtCO = (unsigned short*)(ws + o_wCO);
  unsigned short* wtIP = (unsigned short*)(ws + o_wIP);
  unsigned short* wtXP = (unsigned short*)(ws + o_wXP);
  unsigned short* wtOP = (unsigned short*)(ws + o_wOP);
  unsigned short* wtDT = (unsigned short*)(ws + o_wDT);
  float*          wK7T = (float*)(ws + o_wK7);
  float*          wC4T = (float*)(ws + o_wC4);
  unsigned short* a0H  = (unsigned short*)(ws + o_A0);
  unsigned short* a1H  = (unsigned short*)(ws + o_A1);
  unsigned short* a3H  = (unsigned short*)(ws + o_A3);
  float*          a4F  = (float*)(ws + o_A4);
  unsigned short* a5H  = (unsigned short*)(ws + o_A5);
  // entropy-phase aliases (used only before experts run)
  float*          dftO   = (float*)(ws + o_A0);              // 65 MB < A0+A1
  unsigned short* xnTH   = (unsigned short*)(ws + o_A3);     // 16.8 MB < 33.5 MB
  unsigned short* dftW   = (unsigned short*)(ws + o_A4);     // 128 KB
  float*          rowent = (float*)(ws + o_A4 + (512<<10));  // 254 KB
  // expert-phase alias: delta bf16 lives in the dead xnT region
  unsigned short* dlH    = (unsigned short*)(ws + o_xnT);    // 33.5 MB < 67 MB

  hipMemsetAsync(ws + o_st, 0, 4096, stream);
  hipMemsetAsync(ws + o_wDT, 0, (size_t)4*DIN_*64*2, stream);

  transpose_cvt<<<dim3(32,16,4),256,0,stream>>>(cin_w,  wtCI, 512, 1024, 1024, 512);
  transpose_cvt<<<dim3(16,32,4),256,0,stream>>>(cout_w, wtCO, 1024, 512, 512, 1024);
  transpose_cvt<<<dim3(64,16,4),256,0,stream>>>(m_in,   wtIP, 512, 2048, 2048, 512);
  transpose_cvt<<<dim3( 4,32,4),256,0,stream>>>(m_xp,   wtXP, 1024, 64, 128, 1024);
  transpose_cvt<<<dim3(16,32,4),256,0,stream>>>(m_op,   wtOP, 1024, 512, 512, 1024);
  transpose_cvt<<<dim3(32, 1,4),256,0,stream>>>(m_dtw,  wtDT, 32, 1024, 1024, 64);
  convw_prep<<<4*7,256,0,stream>>>(ck,   wK7T, DIN_, 7);
  convw_prep<<<4*4,256,0,stream>>>(m_cw, wC4T, DIN_, 4);
  dft_init<<<256,256,0,stream>>>(dftW);

  ln_kernel<<<BT_/64,256,0,stream>>>(x, ln_g, ln_b, xnT, xnTH, xnH);
  dft_gemm<<<dim3(2, NWIN*4),256,0,stream>>>(xnTH, dftW, dftO);
  ent_reduce<<<NWIN*512/4,256,0,stream>>>(dftO, xnTH, rowent);
  ent_stage2<<<NWIN,256,0,stream>>>(rowent, entP);
  gating_kernel<<<BT_/64,256,0,stream>>>(xnT, gate_w, ent_w, ent_b, temp, entP, wfull, gtpe, gavg);

  // conv experts (0..3)
  for (int e=0;e<4;e++){
    gemm_k<E_GELU_BF16><<<dim3(8,128),256,0,stream>>>(
        xnH, DM, wtCI + (size_t)e*DIN_*DM, DM, DM,
        cin_b + (size_t)e*DIN_, nullptr, a0H, DIN_, nullptr, 0, nullptr, nullptr);
    dwconv7_gelu<<<BT_*DIN_/8/256,256,0,stream>>>(a0H, wK7T + (size_t)e*7*DIN_, ck_b + (size_t)e*DIN_, a3H);
    gemm_k<E_MOE><<<dim3(4,128),256,0,stream>>>(
        a3H, DIN_, wtCO + (size_t)e*DM*DIN_, DIN_, DIN_,
        cout_b + (size_t)e*DM, out, nullptr, DM, wfull, e, (e==0)? x : nullptr, nullptr);
  }

  // mamba experts (4..7)
  for (int e=0;e<4;e++){
    gemm_k<E_BF16><<<dim3(16,128),256,0,stream>>>(
        xnH, DM, wtIP + (size_t)e*2048*DM, DM, DM,
        nullptr, nullptr, a0H, DIN_, nullptr, 0, nullptr, a1H);            // u_raw + z split
    dwconv4_silu<<<BT_*DIN_/8/256,256,0,stream>>>(a0H, wC4T + (size_t)e*4*DIN_, m_cb + (size_t)e*DIN_, a3H);
    gemm_k<E_F32><<<dim3(1,128),256,0,stream>>>(
        a3H, DIN_, wtXP + (size_t)e*128*DIN_, DIN_, DIN_,
        nullptr, a4F, a5H, 128, nullptr, 0, nullptr, nullptr);             // dbc (f32 + bf16)
    gemm_k<E_SPLUS><<<dim3(8,128),256,0,stream>>>(
        a5H, 128, wtDT + (size_t)e*DIN_*64, 64, 64,
        m_dtb + (size_t)e*DIN_, nullptr, dlH, DIN_, nullptr, 0, nullptr, nullptr); // delta
    scan_k<<<1024,256,0,stream>>>(a4F, dlH, a3H, a1H,
        m_alog + (size_t)e*DIN_*DSTATE_, m_Dd + (size_t)e*DIN_, a0H);      // y -> a0H
    gemm_k<E_MOE><<<dim3(4,128),256,0,stream>>>(
        a0H, DIN_, wtOP + (size_t)e*DM*DIN_, DIN_, DIN_,
        nullptr, out, nullptr, DM, wfull, 4+e, nullptr, nullptr);
  }

  aux_kernel<<<1,1,0,stream>>>(gtpe, gavg, out);
}